// Round 7
// baseline (406.146 us; speedup 1.0000x reference)
//
#include <hip/hip_runtime.h>
#include <hip/hip_bf16.h>
#include <math.h>

#define BB 64
#define NN 320
#define NT 256
#define NV 32
#define NA 32
#define HIDD 512
#define NHEAD 8
#define FD 64

typedef __attribute__((ext_vector_type(8))) short bf16x8;
typedef __attribute__((ext_vector_type(4))) float floatx4;

// ---------------------------------------------------------------------------
// device-global scratch (stream-ordered producer->consumer):
//   me_g   : adj-masked exp(edge_logits), built once
//   fif/fjf: per-(b,head) attention dot products, written by gemm_h epilogue
//   ti/vi/ac planes: presplit inputs, A-FRAGMENT layout [g][kt][lane][8]
//   x planes: node features between layers, same A-fragment layout (nk=16)
//   bw planes: current weight matrix, B-fragment layout [tg][kt][lane][8]
// Every load anywhere is lane-contiguous 16B. Ht lives in d_ws.
// ---------------------------------------------------------------------------
__device__ float me_g[NN * NN];
__device__ float fif_g[512 * NN];
__device__ float fjf_g[512 * NN];
__device__ unsigned short tihi_g[16384 * 768];
__device__ unsigned short tilo_g[16384 * 768];
__device__ unsigned short vihi_g[2048 * 64];
__device__ unsigned short vilo_g[2048 * 64];
__device__ unsigned short achi_g[2048 * 128];
__device__ unsigned short aclo_g[2048 * 128];
__device__ unsigned short xhi_g[20480 * 512];
__device__ unsigned short xlo_g[20480 * 512];
__device__ unsigned short bwhi_g[512 * 768];
__device__ unsigned short bwlo_g[512 * 768];

__device__ __forceinline__ void split1(float v, unsigned short& h, unsigned short& l) {
    unsigned u = __float_as_uint(v);
    unsigned hu = u & 0xFFFF0000u;
    float lf = v - __uint_as_float(hu);
    h = (unsigned short)(hu >> 16);
    l = (unsigned short)(__float_as_uint(lf) >> 16);
}
__device__ __forceinline__ unsigned pack2(unsigned short a, unsigned short b) {
    return (unsigned)a | ((unsigned)b << 16);
}

// async global->LDS 16B/lane: LDS dest = wave-uniform base + lane*16,
// global src = per-lane address.
typedef const __attribute__((address_space(1))) unsigned int* gas1_t;
typedef __attribute__((address_space(3))) unsigned int* las3_t;
__device__ __forceinline__ void gload_lds16(const void* g, void* s) {
    __builtin_amdgcn_global_load_lds((gas1_t)(unsigned long long)g,
                                     (las3_t)(unsigned)(unsigned long long)s,
                                     16, 0, 0);
}

// ---------------------------------------------------------------------------
// me = adj ? exp(elog) : 0
// ---------------------------------------------------------------------------
__global__ __launch_bounds__(256) void build_me(
    const int* __restrict__ adj, const float* __restrict__ elog)
{
    const int i4 = (blockIdx.x * 256 + threadIdx.x) * 4;
    const int4   a = *(const int4*)&adj[i4];
    const float4 e = *(const float4*)&elog[i4];
    float4 m;
    m.x = a.x ? __expf(e.x) : 0.f;
    m.y = a.y ? __expf(e.y) : 0.f;
    m.z = a.z ? __expf(e.z) : 0.f;
    m.w = a.w ? __expf(e.w) : 0.f;
    *(float4*)&me_g[i4] = m;
}

// ---------------------------------------------------------------------------
// presplit_A: fp32 [M][K] -> split-bf16 A-fragment planes [M/16][nk][64][8].
// ---------------------------------------------------------------------------
__global__ __launch_bounds__(256) void presplit_A(
    const float* __restrict__ src, int M, int K, int nk, int sel)
{
    unsigned short* dh = (sel == 0) ? tihi_g : (sel == 1) ? vihi_g : achi_g;
    unsigned short* dl = (sel == 0) ? tilo_g : (sel == 1) ? vilo_g : aclo_g;
    const unsigned t = blockIdx.x * 256 + threadIdx.x;
    const unsigned lane = t & 63, rec = t >> 6;
    const unsigned kt = rec % (unsigned)nk, g = rec / (unsigned)nk;
    const int row = g * 16 + (lane & 15);
    if (row >= M) return;
    const int k0 = kt * 32 + ((lane >> 4) << 3);
    float v[8];
    if (((K & 3) == 0) && (k0 + 8 <= K)) {
        *(float4*)&v[0] = *(const float4*)&src[(size_t)row * K + k0];
        *(float4*)&v[4] = *(const float4*)&src[(size_t)row * K + k0 + 4];
    } else {
#pragma unroll
        for (int e = 0; e < 8; e++) v[e] = (k0 + e < K) ? src[(size_t)row * K + k0 + e] : 0.f;
    }
    unsigned short h[8], l[8];
#pragma unroll
    for (int e = 0; e < 8; e++) split1(v[e], h[e], l[e]);
    const size_t o = (size_t)t * 8;
    *(uint4*)&dh[o] = make_uint4(pack2(h[0],h[1]), pack2(h[2],h[3]),
                                 pack2(h[4],h[5]), pack2(h[6],h[7]));
    *(uint4*)&dl[o] = make_uint4(pack2(l[0],l[1]), pack2(l[2],l[3]),
                                 pack2(l[4],l[5]), pack2(l[6],l[7]));
}

// ---------------------------------------------------------------------------
// presplit_B: weight fp32 -> split-bf16 B-fragment planes [tg][kt][64][8]:
//   col = tg*16+(lane&15), k = kt*32+(lane>>4)*8+e. Zero-pads k >= K.
// wg_mode 0: W row-major [K][512]. wg_mode 1: W = Wg_l [head][512][64].
// ---------------------------------------------------------------------------
__global__ __launch_bounds__(64) void presplit_B(
    const float* __restrict__ W, int K, int Kp, int wg_mode)
{
    const int lane = threadIdx.x;
    const int nt = blockIdx.x, kt = blockIdx.y;
    const int col = nt * 16 + (lane & 15);
    const int k0 = kt * 32 + (lane >> 4) * 8;
    unsigned short h[8], l[8];
#pragma unroll
    for (int e = 0; e < 8; e++) {
        const int k = k0 + e;
        float v = 0.f;
        if (k < K) v = wg_mode ? W[(size_t)(col >> 6) * (512 * 64) + (size_t)k * 64 + (col & 63)]
                               : W[(size_t)k * 512 + col];
        split1(v, h[e], l[e]);
    }
    const size_t o = (((size_t)nt * (Kp >> 5) + kt) * 64 + lane) * 8;
    *(uint4*)&bwhi_g[o] = make_uint4(pack2(h[0], h[1]), pack2(h[2], h[3]),
                                     pack2(h[4], h[5]), pack2(h[6], h[7]));
    *(uint4*)&bwlo_g[o] = make_uint4(pack2(l[0], l[1]), pack2(l[2], l[3]),
                                     pack2(l[4], l[5]), pack2(l[6], l[7]));
}

// ---------------------------------------------------------------------------
// gemm_lds v2 (T3-minimal 2-phase): 128x128 tile, BK=32, 4 waves each 64x64,
// 3-pass split-bf16. DOUBLE-buffered LDS stage (2 x 32KB): per kt, issue the
// 8 global_load_lds for kt+1 into buf^1 BEFORE computing buf (loads fly
// under ds_read+MFMA ~430cy); one vmcnt(0)+barrier per kt (the implicit
// drain in __syncthreads). Race-safe: buf^1 was last ds_read at kt-1, all
// reads drained by kt-1's trailing barrier.
// b_mode 0: proj epilogue -> x fragment planes via per-wave LDS transpose
//           (reuses stage after a barrier).
// b_mode 1: gemm_h -> Ht fragment epilogue + fi/fj fold.
// ---------------------------------------------------------------------------
#define GMFMA(AH, AL, BH, BL)                                                  \
  _Pragma("unroll") for (int s = 0; s < 4; s++)                                \
  _Pragma("unroll") for (int t = 0; t < 4; t++) {                              \
      acc[s][t] = __builtin_amdgcn_mfma_f32_16x16x32_bf16(AH[s], BH[t], acc[s][t], 0, 0, 0); \
      acc[s][t] = __builtin_amdgcn_mfma_f32_16x16x32_bf16(AH[s], BL[t], acc[s][t], 0, 0, 0); \
      acc[s][t] = __builtin_amdgcn_mfma_f32_16x16x32_bf16(AL[s], BH[t], acc[s][t], 0, 0, 0); }

__global__ __launch_bounds__(256, 2) void gemm_lds(
    unsigned short* __restrict__ Hthi, unsigned short* __restrict__ Htlo,
    const float* __restrict__ asrc, const float* __restrict__ adst,
    int nk, int a_sel, int b_mode, int rpb, int noff)
{
    __shared__ __align__(16) unsigned short stage[2][32 * 512];   // 64 KB

    const unsigned short* Ahi = (a_sel == 0) ? tihi_g : (a_sel == 1) ? vihi_g
                              : (a_sel == 2) ? achi_g : xhi_g;
    const unsigned short* Alo = (a_sel == 0) ? tilo_g : (a_sel == 1) ? vilo_g
                              : (a_sel == 2) ? aclo_g : xlo_g;

    const int tid = threadIdx.x, lane = tid & 63, w = tid >> 6;
    const int rw = w >> 1, cw = w & 1;
    const int m0 = blockIdx.x * 128, n0 = blockIdx.y * 128;
    const int g0 = m0 >> 4, tg0 = n0 >> 4;

    // staging: wave w owns one plane (0:Ahi 1:Alo 2:Bhi 3:Blo), 8 records
    const unsigned short* plane = (w == 0) ? Ahi : (w == 1) ? Alo
                                : (w == 2) ? bwhi_g : bwlo_g;
    const unsigned rec0 = (w < 2) ? (unsigned)g0 : (unsigned)tg0;
    const unsigned short* wsrc = plane + (size_t)rec0 * nk * 512 + lane * 8;
    const int woff = (w * 8) * 512;

    floatx4 acc[4][4];
#pragma unroll
    for (int s = 0; s < 4; s++)
#pragma unroll
        for (int t = 0; t < 4; t++) acc[s][t] = (floatx4)0.f;

    // prologue: stage kt=0 into buf 0
#pragma unroll
    for (int u = 0; u < 8; u++)
        gload_lds16(wsrc + ((size_t)u * nk) * 512, &stage[0][woff + u * 512]);
    __syncthreads();   // vmcnt(0) drain: buf0 landed

    int cur = 0;
    for (int kt = 0; kt < nk; ++kt) {
        // issue next tile's loads first (fly under this tile's compute)
        if (kt + 1 < nk) {
            unsigned short* nb = &stage[cur ^ 1][woff];
#pragma unroll
            for (int u = 0; u < 8; u++)
                gload_lds16(wsrc + ((size_t)u * nk + kt + 1) * 512, nb + u * 512);
        }
        const unsigned short* sb = &stage[cur][0];
        bf16x8 a_h[4], a_l[4], b_h[4], b_l[4];
#pragma unroll
        for (int s = 0; s < 4; s++) {
            a_h[s] = *(const bf16x8*)&sb[(rw * 4 + s) * 512 + lane * 8];
            a_l[s] = *(const bf16x8*)&sb[(8 + rw * 4 + s) * 512 + lane * 8];
        }
#pragma unroll
        for (int t = 0; t < 4; t++) {
            b_h[t] = *(const bf16x8*)&sb[(16 + cw * 4 + t) * 512 + lane * 8];
            b_l[t] = *(const bf16x8*)&sb[(24 + cw * 4 + t) * 512 + lane * 8];
        }
        GMFMA(a_h, a_l, b_h, b_l);
        __syncthreads();   // drains vmcnt(0) (kt+1 loads) + all ds_reads of buf
        cur ^= 1;
    }

    const int fq = lane & 15, rl = lane >> 4;

    if (b_mode == 0) {
        // ---- proj epilogue: D -> x fragment planes via LDS transpose ----
        float (*sl)[68] = (float (*)[68])(&stage[0][w * 2176]);   // 16x68 fp32
        const int ktg0 = (n0 + cw * 64) >> 5;     // x k-tile base (x nk = 16)
#pragma unroll
        for (int s = 0; s < 4; s++) {
#pragma unroll
            for (int t = 0; t < 4; t++)
#pragma unroll
                for (int r = 0; r < 4; r++)
                    sl[rl * 4 + r][t * 16 + fq] = acc[s][t][r];
            const int grow16 = m0 + rw * 64 + s * 16;
            const int b = grow16 / rpb;
            const int rr = grow16 - b * rpb;
            const unsigned g = (unsigned)b * 20 + (unsigned)((noff + rr) >> 4);
#pragma unroll
            for (int kth = 0; kth < 2; kth++) {
                float f[8];
                *(float4*)&f[0] = *(const float4*)&sl[fq][kth * 32 + rl * 8];
                *(float4*)&f[4] = *(const float4*)&sl[fq][kth * 32 + rl * 8 + 4];
                unsigned short h[8], l[8];
#pragma unroll
                for (int e = 0; e < 8; e++) split1(f[e], h[e], l[e]);
                const size_t o = (((size_t)g * 16 + ktg0 + kth) * 64 + lane) * 8;
                *(uint4*)&xhi_g[o] = make_uint4(pack2(h[0],h[1]), pack2(h[2],h[3]),
                                                pack2(h[4],h[5]), pack2(h[6],h[7]));
                *(uint4*)&xlo_g[o] = make_uint4(pack2(l[0],l[1]), pack2(l[2],l[3]),
                                                pack2(l[4],l[5]), pack2(l[6],l[7]));
            }
        }
    } else {
        // ---- Ht fragment-layout split-bf16 epilogue ----
        const int hd = (n0 + cw * 64) >> 6;
#pragma unroll
        for (int s = 0; s < 4; s++) {
            const int m_s = m0 + rw * 64 + s * 16 + rl * 4;   // rows m_s..m_s+3
            const unsigned b = (unsigned)m_s / 320u;
            const int jb = m_s - b * 320;
            const int ks = jb >> 5;
            const int jg2 = (jb >> 3) & 3;
            const int eb = jb & 7;
            const size_t slabo = (size_t)b * 8 + hd;
#pragma unroll
            for (int t = 0; t < 4; t++) {
                unsigned short h0,h1,h2,h3,l0,l1,l2,l3;
                split1(acc[s][t][0],h0,l0); split1(acc[s][t][1],h1,l1);
                split1(acc[s][t][2],h2,l2); split1(acc[s][t][3],h3,l3);
                const size_t base = (((slabo * 10 + ks) * 4 + t) * 512
                                     + (size_t)(fq | (jg2 << 4)) * 8) + eb;
                *(uint2*)&Hthi[base] = make_uint2(pack2(h0,h1), pack2(h2,h3));
                *(uint2*)&Htlo[base] = make_uint2(pack2(l0,l1), pack2(l2,l3));
            }
        }
        // fi/fj fold: exact fp32 dot(H_row, a_src/a_dst) per (row, head)
        float as4[4], ad4[4];
#pragma unroll
        for (int t = 0; t < 4; t++) {
            as4[t] = asrc[hd * 64 + t * 16 + fq];
            ad4[t] = adst[hd * 64 + t * 16 + fq];
        }
#pragma unroll
        for (int s = 0; s < 4; s++) {
            const int m_s = m0 + rw * 64 + s * 16 + rl * 4;
            const unsigned b = (unsigned)m_s / 320u;
            const int jb = m_s - b * 320;
            float4 fi4, fj4;
#pragma unroll
            for (int r = 0; r < 4; r++) {
                float fi = (acc[s][0][r]*as4[0] + acc[s][1][r]*as4[1])
                         + (acc[s][2][r]*as4[2] + acc[s][3][r]*as4[3]);
                float fj = (acc[s][0][r]*ad4[0] + acc[s][1][r]*ad4[1])
                         + (acc[s][2][r]*ad4[2] + acc[s][3][r]*ad4[3]);
#pragma unroll
                for (int d = 1; d < 16; d <<= 1) {
                    fi += __shfl_xor(fi, d);
                    fj += __shfl_xor(fj, d);
                }
                ((float*)&fi4)[r] = fi; ((float*)&fj4)[r] = fj;
            }
            if (fq == 0) {
                const size_t o = ((size_t)b * 8 + hd) * NN + jb;
                *(float4*)&fif_g[o] = fi4;
                *(float4*)&fjf_g[o] = fj4;
            }
        }
    }
}

// ---------------------------------------------------------------------------
// MFMA GAT attention: grid (512, 2), 4 blocks/CU. v5: B-frags for ALL nt
// hoisted to the top of the ks loop (8 global loads fly under ~800cy of
// phase-1 VALU); s_setprio(1) around the MFMA cluster (T5: waves drift,
// barrier-free main loop). final_out=0: elu -> x fragment planes.
// final_out=1: fp32 -> d_out.
// ---------------------------------------------------------------------------
template<int IP0, int NIP>
__device__ __forceinline__ void attn_body(
    const unsigned short* __restrict__ Hthi, const unsigned short* __restrict__ Htlo,
    float* __restrict__ xout, int final_out, float* fjs, float* ls,
    float (*slabA)[16][68])
{
    const int bh = blockIdx.x;          // b*8 + hd
    const int hd = bh & 7, b = bh >> 3;
    const int tid = threadIdx.x, lane = tid & 63, w = tid >> 6;
    const int fq = lane & 15, jg = lane >> 4;

    for (int r = tid; r < NN; r += 256) fjs[r] = fjf_g[bh * NN + r];

    float fir[NIP];
#pragma unroll
    for (int ip = 0; ip < NIP; ip++)
        fir[ip] = fif_g[bh * NN + (IP0 + ip) * 64 + (w << 4) + fq];
    __syncthreads();

    floatx4 acc[NIP][4];
#pragma unroll
    for (int ip = 0; ip < NIP; ip++)
#pragma unroll
        for (int nt = 0; nt < 4; nt++) acc[ip][nt] = (floatx4)0.f;
    float lacc[NIP];
#pragma unroll
    for (int ip = 0; ip < NIP; ip++) lacc[ip] = 0.f;

    for (int ks = 0; ks < 10; ks++) {
        // ---- issue B-frag loads for all 4 f-tiles up front ----
        bf16x8 bhf[4], blf[4];
#pragma unroll
        for (int nt = 0; nt < 4; nt++) {
            const unsigned off = (((unsigned)bh * 10 + ks) * 4 + nt) * 512 + (unsigned)lane * 8;
            bhf[nt] = *(const bf16x8*)&Hthi[off];
            blf[nt] = *(const bf16x8*)&Htlo[off];
        }

        const int j8 = ks * 32 + jg * 8;
        const float4 fj0 = *(const float4*)&fjs[j8];
        const float4 fj1 = *(const float4*)&fjs[j8 + 4];

        // ---- phase 1: scores -> exp*me -> split-bf16 A-frags ----
        bf16x8 ahh[NIP], all[NIP];
#pragma unroll
        for (int ip = 0; ip < NIP; ip++) {
            const int i = (IP0 + ip) * 64 + (w << 4) + fq;
            const float fiv = fir[ip];
            const unsigned g = (unsigned)i * NN + j8;
            const float4 m0 = *(const float4*)&me_g[g];
            const float4 m1 = *(const float4*)&me_g[g + 4];
            float p[8];
            {
                float s;
                s = fiv + fj0.x; s = fmaxf(s, 0.2f*s); p[0] = __expf(s) * m0.x;
                s = fiv + fj0.y; s = fmaxf(s, 0.2f*s); p[1] = __expf(s) * m0.y;
                s = fiv + fj0.z; s = fmaxf(s, 0.2f*s); p[2] = __expf(s) * m0.z;
                s = fiv + fj0.w; s = fmaxf(s, 0.2f*s); p[3] = __expf(s) * m0.w;
                s = fiv + fj1.x; s = fmaxf(s, 0.2f*s); p[4] = __expf(s) * m1.x;
                s = fiv + fj1.y; s = fmaxf(s, 0.2f*s); p[5] = __expf(s) * m1.y;
                s = fiv + fj1.z; s = fmaxf(s, 0.2f*s); p[6] = __expf(s) * m1.z;
                s = fiv + fj1.w; s = fmaxf(s, 0.2f*s); p[7] = __expf(s) * m1.w;
            }
            lacc[ip] += ((p[0]+p[1]) + (p[2]+p[3])) + ((p[4]+p[5]) + (p[6]+p[7]));

            unsigned short ph[8], pl[8];
#pragma unroll
            for (int e = 0; e < 8; e++) split1(p[e], ph[e], pl[e]);
            union { uint4 u; bf16x8 v; } ua, ul;
            ua.u = make_uint4(pack2(ph[0],ph[1]), pack2(ph[2],ph[3]),
                              pack2(ph[4],ph[5]), pack2(ph[6],ph[7]));
            ul.u = make_uint4(pack2(pl[0],pl[1]), pack2(pl[2],pl[3]),
                              pack2(pl[4],pl[5]), pack2(pl[6],pl[7]));
            ahh[ip] = ua.v; all[ip] = ul.v;
        }

        // ---- phase 2: MFMA cluster, prioritized ----
        __builtin_amdgcn_s_setprio(1);
#pragma unroll
        for (int nt = 0; nt < 4; nt++)
#pragma unroll
            for (int ip = 0; ip < NIP; ip++) {
                acc[ip][nt] = __builtin_amdgcn_mfma_f32_16x16x32_bf16(ahh[ip], bhf[nt], acc[ip][nt], 0, 0, 0);
                acc[ip][nt] = __builtin_amdgcn_mfma_f32_16x16x32_bf16(ahh[ip], blf[nt], acc[ip][nt], 0, 0, 0);
                acc[ip][nt] = __builtin_amdgcn_mfma_f32_16x16x32_bf16(all[ip], bhf[nt], acc[ip][nt], 0, 0, 0);
            }
        __builtin_amdgcn_s_setprio(0);
    }

    // ---- l reduction: sum over the 4 jg lanes holding the same i ----
#pragma unroll
    for (int ip = 0; ip < NIP; ip++) {
        float l = lacc[ip];
        l += __shfl_xor(l, 16);
        l += __shfl_xor(l, 32);
        if (jg == 0) ls[(IP0 + ip) * 64 + (w << 4) + fq] = l;
    }
    __syncthreads();

    // ---- epilogue: D col(f)=fq, row(i)=jg*4+r ----
    if (final_out) {
#pragma unroll
        for (int ip = 0; ip < NIP; ip++) {
            const int ib = ((IP0 + ip) * 4 + w) * 16 + jg * 4;
#pragma unroll
            for (int r = 0; r < 4; r++) {
                const float lv = ls[ib + r];
                const float inv = (lv > 0.f) ? 1.f / lv : 0.f;
                const size_t ro = ((size_t)(b * NN + ib + r)) * HIDD + hd * 64;
#pragma unroll
                for (int nt = 0; nt < 4; nt++)
                    xout[ro + nt * 16 + fq] = acc[ip][nt][r] * inv;
            }
        }
    } else {
        // elu + write x fragment planes via per-wave LDS transpose
        float (*sl)[68] = slabA[w];
        const int ktg0 = hd * 2;
#pragma unroll
        for (int ip = 0; ip < NIP; ip++) {
            const int ib = ((IP0 + ip) * 4 + w) * 16 + jg * 4;
#pragma unroll
            for (int r = 0; r < 4; r++) {
                const float lv = ls[ib + r];
                const float inv = (lv > 0.f) ? 1.f / lv : 0.f;
#pragma unroll
                for (int nt = 0; nt < 4; nt++) {
                    float vv = acc[ip][nt][r] * inv;
                    vv = (vv > 0.f) ? vv : __expf(vv) - 1.f;   // elu
                    sl[jg * 4 + r][nt * 16 + fq] = vv;
                }
            }
            const unsigned g = (unsigned)b * 20 + (IP0 + ip) * 4 + w;
#pragma unroll
            for (int kth = 0; kth < 2; kth++) {
                float f[8];
                *(float4*)&f[0] = *(const float4*)&sl[fq][kth * 32 + jg * 8];
                *(float4*)&f[4] = *(const float4*)&sl[fq][kth * 32 + jg * 8 + 4];
                unsigned short h[8], l[8];
#pragma unroll
                for (int e = 0; e < 8; e++) split1(f[e], h[e], l[e]);
                const size_t o = (((size_t)g * 16 + ktg0 + kth) * 64 + lane) * 8;
                *(uint4*)&xhi_g[o] = make_uint4(pack2(h[0],h[1]), pack2(h[2],h[3]),
                                                pack2(h[4],h[5]), pack2(h[6],h[7]));
                *(uint4*)&xlo_g[o] = make_uint4(pack2(l[0],l[1]), pack2(l[2],l[3]),
                                                pack2(l[4],l[5]), pack2(l[6],l[7]));
            }
        }
    }
}

__global__ __launch_bounds__(256, 4) void attn_mfma(
    const unsigned short* __restrict__ Hthi, const unsigned short* __restrict__ Htlo,
    float* __restrict__ xout, int final_out)
{
    __shared__ float fjs[NN];
    __shared__ float ls[NN];
    __shared__ float slabA[4][16][68];
    if (blockIdx.y == 0) attn_body<0, 3>(Hthi, Htlo, xout, final_out, fjs, ls, slabA);
    else                 attn_body<3, 2>(Hthi, Htlo, xout, final_out, fjs, ls, slabA);
}

// ---------------------------------------------------------------------------
// Flow: build_me; presplit inputs (fragment layout); per matmul: presplit_B
// then gemm_lds. proj -> x planes; per layer: gemm_h -> Ht(ws)+fi/fj;
// attn -> x planes (l=0, elu) / fp32 d_out (l=1). Strictly stream-ordered.
// ---------------------------------------------------------------------------
extern "C" void kernel_launch(void* const* d_in, const int* in_sizes, int n_in,
                              void* d_out, int out_size, void* d_ws, size_t ws_size,
                              hipStream_t stream)
{
    (void)in_sizes; (void)n_in; (void)out_size; (void)ws_size;
    const float* text     = (const float*)d_in[0];
    const float* visual   = (const float*)d_in[1];
    const float* acoustic = (const float*)d_in[2];
    const int*   adj      = (const int*)d_in[3];
    const float* Wt       = (const float*)d_in[4];
    const float* Wv       = (const float*)d_in[5];
    const float* Wa       = (const float*)d_in[6];
    const float* Wg       = (const float*)d_in[7];
    const float* a_src    = (const float*)d_in[8];
    const float* a_dst    = (const float*)d_in[9];
    const float* elog     = (const float*)d_in[10];

    float* xbuf = (float*)d_out;
    unsigned short* Hthi = (unsigned short*)d_ws;
    unsigned short* Htlo = Hthi + (size_t)512 * 10 * 4 * 512;   // 10,485,760 shorts

    build_me<<<NN * NN / 1024, 256, 0, stream>>>(adj, elog);

    // inputs -> fragment planes: grid = M/16 * nk * 64 / 256
    presplit_A<<<(16384 / 16) * 24 * 64 / 256, 256, 0, stream>>>(text,     16384, 768, 24, 0);
    presplit_A<<<(2048  / 16) * 2  * 64 / 256, 256, 0, stream>>>(visual,   2048,  47,  2,  1);
    presplit_A<<<(2048  / 16) * 4  * 64 / 256, 256, 0, stream>>>(acoustic, 2048,  74,  4,  2);

    // projections -> x planes
    presplit_B<<<dim3(32, 768 / 32), 64, 0, stream>>>(Wt, 768, 768, 0);
    gemm_lds<<<dim3((BB*NT)/128, 4), 256, 0, stream>>>(nullptr, nullptr, nullptr, nullptr,
                                                       24, 0, 0, NT, 0);
    presplit_B<<<dim3(32, 64 / 32), 64, 0, stream>>>(Wv, 47, 64, 0);
    gemm_lds<<<dim3((BB*NV)/128, 4), 256, 0, stream>>>(nullptr, nullptr, nullptr, nullptr,
                                                       2, 1, 0, NV, NT);
    presplit_B<<<dim3(32, 128 / 32), 64, 0, stream>>>(Wa, 74, 128, 0);
    gemm_lds<<<dim3((BB*NA)/128, 4), 256, 0, stream>>>(nullptr, nullptr, nullptr, nullptr,
                                                       4, 2, 0, NA, NT + NV);

    for (int l = 0; l < 2; l++) {
        const float* Wg_l = Wg + (size_t)l * NHEAD * HIDD * FD;
        presplit_B<<<dim3(32, 512 / 32), 64, 0, stream>>>(Wg_l, 512, 512, 1);
        gemm_lds<<<dim3((BB*NN)/128, 4), 256, 0, stream>>>(Hthi, Htlo,
            a_src + l * NHEAD * FD, a_dst + l * NHEAD * FD, 16, 3, 1, NN, 0);
        attn_mfma<<<dim3(BB * NHEAD, 2), 256, 0, stream>>>(
            Hthi, Htlo, xbuf, (l == 0) ? 0 : 1);
    }
}

// Round 8
// 385.973 us; speedup vs baseline: 1.0523x; 1.0523x over previous
//
#include <hip/hip_runtime.h>
#include <hip/hip_bf16.h>
#include <math.h>

#define BB 64
#define NN 320
#define NT 256
#define NV 32
#define NA 32
#define HIDD 512
#define NHEAD 8
#define FD 64

typedef __attribute__((ext_vector_type(8))) short bf16x8;
typedef __attribute__((ext_vector_type(4))) float floatx4;

// ---------------------------------------------------------------------------
// device-global scratch (stream-ordered producer->consumer):
//   me_g   : adj-masked exp(edge_logits), built once
//   fif/fjf: per-(b,head) attention dot products, written by gemm_h epilogue
//   ti/vi/ac planes: presplit inputs, A-FRAGMENT layout [g][kt][lane][8]
//   x planes: node features between layers, same A-fragment layout (nk=16)
//   bw planes: current weight matrix, B-fragment layout [tg][kt][lane][8]
// Every load anywhere is lane-contiguous 16B. Ht lives in d_ws.
// ---------------------------------------------------------------------------
__device__ float me_g[NN * NN];
__device__ float fif_g[512 * NN];
__device__ float fjf_g[512 * NN];
__device__ unsigned short tihi_g[16384 * 768];
__device__ unsigned short tilo_g[16384 * 768];
__device__ unsigned short vihi_g[2048 * 64];
__device__ unsigned short vilo_g[2048 * 64];
__device__ unsigned short achi_g[2048 * 128];
__device__ unsigned short aclo_g[2048 * 128];
__device__ unsigned short xhi_g[20480 * 512];
__device__ unsigned short xlo_g[20480 * 512];
__device__ unsigned short bwhi_g[512 * 768];
__device__ unsigned short bwlo_g[512 * 768];

__device__ __forceinline__ void split1(float v, unsigned short& h, unsigned short& l) {
    unsigned u = __float_as_uint(v);
    unsigned hu = u & 0xFFFF0000u;
    float lf = v - __uint_as_float(hu);
    h = (unsigned short)(hu >> 16);
    l = (unsigned short)(__float_as_uint(lf) >> 16);
}
__device__ __forceinline__ unsigned pack2(unsigned short a, unsigned short b) {
    return (unsigned)a | ((unsigned)b << 16);
}

// async global->LDS 16B/lane: LDS dest = wave-uniform base + lane*16,
// global src = per-lane address.
typedef const __attribute__((address_space(1))) unsigned int* gas1_t;
typedef __attribute__((address_space(3))) unsigned int* las3_t;
__device__ __forceinline__ void gload_lds16(const void* g, void* s) {
    __builtin_amdgcn_global_load_lds((gas1_t)(unsigned long long)g,
                                     (las3_t)(unsigned)(unsigned long long)s,
                                     16, 0, 0);
}

// ---------------------------------------------------------------------------
// me = adj ? exp(elog) : 0
// ---------------------------------------------------------------------------
__global__ __launch_bounds__(256) void build_me(
    const int* __restrict__ adj, const float* __restrict__ elog)
{
    const int i4 = (blockIdx.x * 256 + threadIdx.x) * 4;
    const int4   a = *(const int4*)&adj[i4];
    const float4 e = *(const float4*)&elog[i4];
    float4 m;
    m.x = a.x ? __expf(e.x) : 0.f;
    m.y = a.y ? __expf(e.y) : 0.f;
    m.z = a.z ? __expf(e.z) : 0.f;
    m.w = a.w ? __expf(e.w) : 0.f;
    *(float4*)&me_g[i4] = m;
}

// ---------------------------------------------------------------------------
// presplit_A: fp32 [M][K] -> split-bf16 A-fragment planes [M/16][nk][64][8].
// ---------------------------------------------------------------------------
__global__ __launch_bounds__(256) void presplit_A(
    const float* __restrict__ src, int M, int K, int nk, int sel)
{
    unsigned short* dh = (sel == 0) ? tihi_g : (sel == 1) ? vihi_g : achi_g;
    unsigned short* dl = (sel == 0) ? tilo_g : (sel == 1) ? vilo_g : aclo_g;
    const unsigned t = blockIdx.x * 256 + threadIdx.x;
    const unsigned lane = t & 63, rec = t >> 6;
    const unsigned kt = rec % (unsigned)nk, g = rec / (unsigned)nk;
    const int row = g * 16 + (lane & 15);
    if (row >= M) return;
    const int k0 = kt * 32 + ((lane >> 4) << 3);
    float v[8];
    if (((K & 3) == 0) && (k0 + 8 <= K)) {
        *(float4*)&v[0] = *(const float4*)&src[(size_t)row * K + k0];
        *(float4*)&v[4] = *(const float4*)&src[(size_t)row * K + k0 + 4];
    } else {
#pragma unroll
        for (int e = 0; e < 8; e++) v[e] = (k0 + e < K) ? src[(size_t)row * K + k0 + e] : 0.f;
    }
    unsigned short h[8], l[8];
#pragma unroll
    for (int e = 0; e < 8; e++) split1(v[e], h[e], l[e]);
    const size_t o = (size_t)t * 8;
    *(uint4*)&dh[o] = make_uint4(pack2(h[0],h[1]), pack2(h[2],h[3]),
                                 pack2(h[4],h[5]), pack2(h[6],h[7]));
    *(uint4*)&dl[o] = make_uint4(pack2(l[0],l[1]), pack2(l[2],l[3]),
                                 pack2(l[4],l[5]), pack2(l[6],l[7]));
}

// ---------------------------------------------------------------------------
// presplit_B: weight fp32 -> split-bf16 B-fragment planes [tg][kt][64][8]:
//   col = tg*16+(lane&15), k = kt*32+(lane>>4)*8+e. Zero-pads k >= K.
// wg_mode 0: W row-major [K][512]. wg_mode 1: W = Wg_l [head][512][64].
// ---------------------------------------------------------------------------
__global__ __launch_bounds__(64) void presplit_B(
    const float* __restrict__ W, int K, int Kp, int wg_mode)
{
    const int lane = threadIdx.x;
    const int nt = blockIdx.x, kt = blockIdx.y;
    const int col = nt * 16 + (lane & 15);
    const int k0 = kt * 32 + (lane >> 4) * 8;
    unsigned short h[8], l[8];
#pragma unroll
    for (int e = 0; e < 8; e++) {
        const int k = k0 + e;
        float v = 0.f;
        if (k < K) v = wg_mode ? W[(size_t)(col >> 6) * (512 * 64) + (size_t)k * 64 + (col & 63)]
                               : W[(size_t)k * 512 + col];
        split1(v, h[e], l[e]);
    }
    const size_t o = (((size_t)nt * (Kp >> 5) + kt) * 64 + lane) * 8;
    *(uint4*)&bwhi_g[o] = make_uint4(pack2(h[0], h[1]), pack2(h[2], h[3]),
                                     pack2(h[4], h[5]), pack2(h[6], h[7]));
    *(uint4*)&bwlo_g[o] = make_uint4(pack2(l[0], l[1]), pack2(l[2], l[3]),
                                     pack2(l[4], l[5]), pack2(l[6], l[7]));
}

// ---------------------------------------------------------------------------
// gemm_lds (T3-minimal 2-phase): 128x128 tile, BK=32, 4 waves each 64x64,
// 3-pass split-bf16. Double-buffered LDS stage; issue kt+1 loads BEFORE
// computing kt; one vmcnt(0)+barrier per kt (inside __syncthreads).
// b_mode 0: proj epilogue -> x fragment planes via per-wave LDS transpose.
// b_mode 1: gemm_h -> Ht fragment epilogue + fi/fj fold.
// ---------------------------------------------------------------------------
#define GMFMA(AH, AL, BH, BL)                                                  \
  _Pragma("unroll") for (int s = 0; s < 4; s++)                                \
  _Pragma("unroll") for (int t = 0; t < 4; t++) {                              \
      acc[s][t] = __builtin_amdgcn_mfma_f32_16x16x32_bf16(AH[s], BH[t], acc[s][t], 0, 0, 0); \
      acc[s][t] = __builtin_amdgcn_mfma_f32_16x16x32_bf16(AH[s], BL[t], acc[s][t], 0, 0, 0); \
      acc[s][t] = __builtin_amdgcn_mfma_f32_16x16x32_bf16(AL[s], BH[t], acc[s][t], 0, 0, 0); }

__global__ __launch_bounds__(256, 2) void gemm_lds(
    unsigned short* __restrict__ Hthi, unsigned short* __restrict__ Htlo,
    const float* __restrict__ asrc, const float* __restrict__ adst,
    int nk, int a_sel, int b_mode, int rpb, int noff)
{
    __shared__ __align__(16) unsigned short stage[2][32 * 512];   // 64 KB

    const unsigned short* Ahi = (a_sel == 0) ? tihi_g : (a_sel == 1) ? vihi_g
                              : (a_sel == 2) ? achi_g : xhi_g;
    const unsigned short* Alo = (a_sel == 0) ? tilo_g : (a_sel == 1) ? vilo_g
                              : (a_sel == 2) ? aclo_g : xlo_g;

    const int tid = threadIdx.x, lane = tid & 63, w = tid >> 6;
    const int rw = w >> 1, cw = w & 1;
    const int m0 = blockIdx.x * 128, n0 = blockIdx.y * 128;
    const int g0 = m0 >> 4, tg0 = n0 >> 4;

    // staging: wave w owns one plane (0:Ahi 1:Alo 2:Bhi 3:Blo), 8 records
    const unsigned short* plane = (w == 0) ? Ahi : (w == 1) ? Alo
                                : (w == 2) ? bwhi_g : bwlo_g;
    const unsigned rec0 = (w < 2) ? (unsigned)g0 : (unsigned)tg0;
    const unsigned short* wsrc = plane + (size_t)rec0 * nk * 512 + lane * 8;
    const int woff = (w * 8) * 512;

    floatx4 acc[4][4];
#pragma unroll
    for (int s = 0; s < 4; s++)
#pragma unroll
        for (int t = 0; t < 4; t++) acc[s][t] = (floatx4)0.f;

    // prologue: stage kt=0 into buf 0
#pragma unroll
    for (int u = 0; u < 8; u++)
        gload_lds16(wsrc + ((size_t)u * nk) * 512, &stage[0][woff + u * 512]);
    __syncthreads();   // vmcnt(0) drain: buf0 landed

    int cur = 0;
    for (int kt = 0; kt < nk; ++kt) {
        // issue next tile's loads first (fly under this tile's compute)
        if (kt + 1 < nk) {
            unsigned short* nb = &stage[cur ^ 1][woff];
#pragma unroll
            for (int u = 0; u < 8; u++)
                gload_lds16(wsrc + ((size_t)u * nk + kt + 1) * 512, nb + u * 512);
        }
        const unsigned short* sb = &stage[cur][0];
        bf16x8 a_h[4], a_l[4], b_h[4], b_l[4];
#pragma unroll
        for (int s = 0; s < 4; s++) {
            a_h[s] = *(const bf16x8*)&sb[(rw * 4 + s) * 512 + lane * 8];
            a_l[s] = *(const bf16x8*)&sb[(8 + rw * 4 + s) * 512 + lane * 8];
        }
#pragma unroll
        for (int t = 0; t < 4; t++) {
            b_h[t] = *(const bf16x8*)&sb[(16 + cw * 4 + t) * 512 + lane * 8];
            b_l[t] = *(const bf16x8*)&sb[(24 + cw * 4 + t) * 512 + lane * 8];
        }
        GMFMA(a_h, a_l, b_h, b_l);
        __syncthreads();   // drains vmcnt(0) (kt+1 loads) + all ds_reads of buf
        cur ^= 1;
    }

    const int fq = lane & 15, rl = lane >> 4;

    if (b_mode == 0) {
        // ---- proj epilogue: D -> x fragment planes via LDS transpose ----
        float (*sl)[68] = (float (*)[68])(&stage[0][w * 2176]);   // 16x68 fp32
        const int ktg0 = (n0 + cw * 64) >> 5;     // x k-tile base (x nk = 16)
#pragma unroll
        for (int s = 0; s < 4; s++) {
#pragma unroll
            for (int t = 0; t < 4; t++)
#pragma unroll
                for (int r = 0; r < 4; r++)
                    sl[rl * 4 + r][t * 16 + fq] = acc[s][t][r];
            const int grow16 = m0 + rw * 64 + s * 16;
            const int b = grow16 / rpb;
            const int rr = grow16 - b * rpb;
            const unsigned g = (unsigned)b * 20 + (unsigned)((noff + rr) >> 4);
#pragma unroll
            for (int kth = 0; kth < 2; kth++) {
                float f[8];
                *(float4*)&f[0] = *(const float4*)&sl[fq][kth * 32 + rl * 8];
                *(float4*)&f[4] = *(const float4*)&sl[fq][kth * 32 + rl * 8 + 4];
                unsigned short h[8], l[8];
#pragma unroll
                for (int e = 0; e < 8; e++) split1(f[e], h[e], l[e]);
                const size_t o = (((size_t)g * 16 + ktg0 + kth) * 64 + lane) * 8;
                *(uint4*)&xhi_g[o] = make_uint4(pack2(h[0],h[1]), pack2(h[2],h[3]),
                                                pack2(h[4],h[5]), pack2(h[6],h[7]));
                *(uint4*)&xlo_g[o] = make_uint4(pack2(l[0],l[1]), pack2(l[2],l[3]),
                                                pack2(l[4],l[5]), pack2(l[6],l[7]));
            }
        }
    } else {
        // ---- Ht fragment-layout split-bf16 epilogue ----
        const int hd = (n0 + cw * 64) >> 6;
#pragma unroll
        for (int s = 0; s < 4; s++) {
            const int m_s = m0 + rw * 64 + s * 16 + rl * 4;   // rows m_s..m_s+3
            const unsigned b = (unsigned)m_s / 320u;
            const int jb = m_s - b * 320;
            const int ks = jb >> 5;
            const int jg2 = (jb >> 3) & 3;
            const int eb = jb & 7;
            const size_t slabo = (size_t)b * 8 + hd;
#pragma unroll
            for (int t = 0; t < 4; t++) {
                unsigned short h0,h1,h2,h3,l0,l1,l2,l3;
                split1(acc[s][t][0],h0,l0); split1(acc[s][t][1],h1,l1);
                split1(acc[s][t][2],h2,l2); split1(acc[s][t][3],h3,l3);
                const size_t base = (((slabo * 10 + ks) * 4 + t) * 512
                                     + (size_t)(fq | (jg2 << 4)) * 8) + eb;
                *(uint2*)&Hthi[base] = make_uint2(pack2(h0,h1), pack2(h2,h3));
                *(uint2*)&Htlo[base] = make_uint2(pack2(l0,l1), pack2(l2,l3));
            }
        }
        // fi/fj fold: exact fp32 dot(H_row, a_src/a_dst) per (row, head)
        float as4[4], ad4[4];
#pragma unroll
        for (int t = 0; t < 4; t++) {
            as4[t] = asrc[hd * 64 + t * 16 + fq];
            ad4[t] = adst[hd * 64 + t * 16 + fq];
        }
#pragma unroll
        for (int s = 0; s < 4; s++) {
            const int m_s = m0 + rw * 64 + s * 16 + rl * 4;
            const unsigned b = (unsigned)m_s / 320u;
            const int jb = m_s - b * 320;
            float4 fi4, fj4;
#pragma unroll
            for (int r = 0; r < 4; r++) {
                float fi = (acc[s][0][r]*as4[0] + acc[s][1][r]*as4[1])
                         + (acc[s][2][r]*as4[2] + acc[s][3][r]*as4[3]);
                float fj = (acc[s][0][r]*ad4[0] + acc[s][1][r]*ad4[1])
                         + (acc[s][2][r]*ad4[2] + acc[s][3][r]*ad4[3]);
#pragma unroll
                for (int d = 1; d < 16; d <<= 1) {
                    fi += __shfl_xor(fi, d);
                    fj += __shfl_xor(fj, d);
                }
                ((float*)&fi4)[r] = fi; ((float*)&fj4)[r] = fj;
            }
            if (fq == 0) {
                const size_t o = ((size_t)b * 8 + hd) * NN + jb;
                *(float4*)&fif_g[o] = fi4;
                *(float4*)&fjf_g[o] = fj4;
            }
        }
    }
}

// ---------------------------------------------------------------------------
// MFMA GAT attention v6: grid (512, 5) = 2560 small blocks, NIP=1 each
// (blockIdx.y = ip). launch_bounds(256,6) -> ~85 regs, 6 blocks/CU = 24
// waves/CU for latency hiding (r6 was ~10.6). B-frags loaded per-nt inside
// the MFMA phase (r7's hoist spilled -> reverted). l via in-wave shfl (no
// ls LDS, no trailing barrier). setprio(1) around MFMA cluster (T5).
// final_out=0: elu -> x fragment planes.  final_out=1: fp32 -> d_out.
// ---------------------------------------------------------------------------
__global__ __launch_bounds__(256, 6) void attn_mfma(
    const unsigned short* __restrict__ Hthi, const unsigned short* __restrict__ Htlo,
    float* __restrict__ xout, int final_out)
{
    __shared__ float fjs[NN];
    __shared__ float slabA[4][16][68];

    const int bh = blockIdx.x;          // b*8 + hd
    const int ip = blockIdx.y;          // i-panel 0..4 (64 rows each)
    const int hd = bh & 7, b = bh >> 3;
    const int tid = threadIdx.x, lane = tid & 63, w = tid >> 6;
    const int fq = lane & 15, jg = lane >> 4;

    for (int r = tid; r < NN; r += 256) fjs[r] = fjf_g[bh * NN + r];
    const float fiv = fif_g[bh * NN + ip * 64 + (w << 4) + fq];
    __syncthreads();

    floatx4 acc[4];
#pragma unroll
    for (int nt = 0; nt < 4; nt++) acc[nt] = (floatx4)0.f;
    float lacc = 0.f;

    for (int ks = 0; ks < 10; ks++) {
        const int j8 = ks * 32 + jg * 8;
        const float4 fj0 = *(const float4*)&fjs[j8];
        const float4 fj1 = *(const float4*)&fjs[j8 + 4];

        // ---- phase 1: scores -> exp*me -> split-bf16 A-frag ----
        const unsigned g = (unsigned)(ip * 64 + (w << 4) + fq) * NN + j8;
        const float4 m0 = *(const float4*)&me_g[g];
        const float4 m1 = *(const float4*)&me_g[g + 4];
        float p[8];
        {
            float s;
            s = fiv + fj0.x; s = fmaxf(s, 0.2f*s); p[0] = __expf(s) * m0.x;
            s = fiv + fj0.y; s = fmaxf(s, 0.2f*s); p[1] = __expf(s) * m0.y;
            s = fiv + fj0.z; s = fmaxf(s, 0.2f*s); p[2] = __expf(s) * m0.z;
            s = fiv + fj0.w; s = fmaxf(s, 0.2f*s); p[3] = __expf(s) * m0.w;
            s = fiv + fj1.x; s = fmaxf(s, 0.2f*s); p[4] = __expf(s) * m1.x;
            s = fiv + fj1.y; s = fmaxf(s, 0.2f*s); p[5] = __expf(s) * m1.y;
            s = fiv + fj1.z; s = fmaxf(s, 0.2f*s); p[6] = __expf(s) * m1.z;
            s = fiv + fj1.w; s = fmaxf(s, 0.2f*s); p[7] = __expf(s) * m1.w;
        }
        lacc += ((p[0]+p[1]) + (p[2]+p[3])) + ((p[4]+p[5]) + (p[6]+p[7]));

        unsigned short ph[8], pl[8];
#pragma unroll
        for (int e = 0; e < 8; e++) split1(p[e], ph[e], pl[e]);
        union { uint4 u; bf16x8 v; } ua, ul;
        ua.u = make_uint4(pack2(ph[0],ph[1]), pack2(ph[2],ph[3]),
                          pack2(ph[4],ph[5]), pack2(ph[6],ph[7]));
        ul.u = make_uint4(pack2(pl[0],pl[1]), pack2(pl[2],pl[3]),
                          pack2(pl[4],pl[5]), pack2(pl[6],pl[7]));
        const bf16x8 ahh = ua.v, all = ul.v;

        // ---- phase 2: per f-tile, load B pair then 3 MFMAs ----
        __builtin_amdgcn_s_setprio(1);
#pragma unroll
        for (int nt = 0; nt < 4; nt++) {
            const unsigned off = (((unsigned)bh * 10 + ks) * 4 + nt) * 512 + (unsigned)lane * 8;
            const bf16x8 bhf = *(const bf16x8*)&Hthi[off];
            const bf16x8 blf = *(const bf16x8*)&Htlo[off];
            acc[nt] = __builtin_amdgcn_mfma_f32_16x16x32_bf16(ahh, bhf, acc[nt], 0, 0, 0);
            acc[nt] = __builtin_amdgcn_mfma_f32_16x16x32_bf16(ahh, blf, acc[nt], 0, 0, 0);
            acc[nt] = __builtin_amdgcn_mfma_f32_16x16x32_bf16(all, bhf, acc[nt], 0, 0, 0);
        }
        __builtin_amdgcn_s_setprio(0);
    }

    // ---- l: reduce over the 4 jg lanes holding the same row (in-wave) ----
    lacc += __shfl_xor(lacc, 16);
    lacc += __shfl_xor(lacc, 32);   // lane x now holds l for row (x&15)

    // ---- epilogue: D col(f)=fq, row(i)=jg*4+r ----
    if (final_out) {
#pragma unroll
        for (int r = 0; r < 4; r++) {
            const float lv = __shfl(lacc, jg * 4 + r);
            const float inv = (lv > 0.f) ? 1.f / lv : 0.f;
            const int ib = (ip * 4 + w) * 16 + jg * 4 + r;
            const size_t ro = ((size_t)(b * NN + ib)) * HIDD + hd * 64;
#pragma unroll
            for (int nt = 0; nt < 4; nt++)
                xout[ro + nt * 16 + fq] = acc[nt][r] * inv;
        }
    } else {
        // elu + write x fragment planes via per-wave LDS transpose
        float (*sl)[68] = slabA[w];
        const int ktg0 = hd * 2;
#pragma unroll
        for (int r = 0; r < 4; r++) {
            const float lv = __shfl(lacc, jg * 4 + r);
            const float inv = (lv > 0.f) ? 1.f / lv : 0.f;
#pragma unroll
            for (int nt = 0; nt < 4; nt++) {
                float vv = acc[nt][r] * inv;
                vv = (vv > 0.f) ? vv : __expf(vv) - 1.f;   // elu
                sl[jg * 4 + r][nt * 16 + fq] = vv;
            }
        }
        const unsigned g = (unsigned)b * 20 + ip * 4 + w;
#pragma unroll
        for (int kth = 0; kth < 2; kth++) {
            float f[8];
            *(float4*)&f[0] = *(const float4*)&sl[fq][kth * 32 + jg * 8];
            *(float4*)&f[4] = *(const float4*)&sl[fq][kth * 32 + jg * 8 + 4];
            unsigned short h[8], l[8];
#pragma unroll
            for (int e = 0; e < 8; e++) split1(f[e], h[e], l[e]);
            const size_t o = (((size_t)g * 16 + ktg0 + kth) * 64 + lane) * 8;
            *(uint4*)&xhi_g[o] = make_uint4(pack2(h[0],h[1]), pack2(h[2],h[3]),
                                            pack2(h[4],h[5]), pack2(h[6],h[7]));
            *(uint4*)&xlo_g[o] = make_uint4(pack2(l[0],l[1]), pack2(l[2],l[3]),
                                            pack2(l[4],l[5]), pack2(l[6],l[7]));
        }
    }
}

// ---------------------------------------------------------------------------
// Flow: build_me; presplit inputs (fragment layout); per matmul: presplit_B
// then gemm_lds. proj -> x planes; per layer: gemm_h -> Ht(ws)+fi/fj;
// attn -> x planes (l=0, elu) / fp32 d_out (l=1). Strictly stream-ordered.
// ---------------------------------------------------------------------------
extern "C" void kernel_launch(void* const* d_in, const int* in_sizes, int n_in,
                              void* d_out, int out_size, void* d_ws, size_t ws_size,
                              hipStream_t stream)
{
    (void)in_sizes; (void)n_in; (void)out_size; (void)ws_size;
    const float* text     = (const float*)d_in[0];
    const float* visual   = (const float*)d_in[1];
    const float* acoustic = (const float*)d_in[2];
    const int*   adj      = (const int*)d_in[3];
    const float* Wt       = (const float*)d_in[4];
    const float* Wv       = (const float*)d_in[5];
    const float* Wa       = (const float*)d_in[6];
    const float* Wg       = (const float*)d_in[7];
    const float* a_src    = (const float*)d_in[8];
    const float* a_dst    = (const float*)d_in[9];
    const float* elog     = (const float*)d_in[10];

    float* xbuf = (float*)d_out;
    unsigned short* Hthi = (unsigned short*)d_ws;
    unsigned short* Htlo = Hthi + (size_t)512 * 10 * 4 * 512;   // 10,485,760 shorts

    build_me<<<NN * NN / 1024, 256, 0, stream>>>(adj, elog);

    // inputs -> fragment planes: grid = M/16 * nk * 64 / 256
    presplit_A<<<(16384 / 16) * 24 * 64 / 256, 256, 0, stream>>>(text,     16384, 768, 24, 0);
    presplit_A<<<(2048  / 16) * 2  * 64 / 256, 256, 0, stream>>>(visual,   2048,  47,  2,  1);
    presplit_A<<<(2048  / 16) * 4  * 64 / 256, 256, 0, stream>>>(acoustic, 2048,  74,  4,  2);

    // projections -> x planes
    presplit_B<<<dim3(32, 768 / 32), 64, 0, stream>>>(Wt, 768, 768, 0);
    gemm_lds<<<dim3((BB*NT)/128, 4), 256, 0, stream>>>(nullptr, nullptr, nullptr, nullptr,
                                                       24, 0, 0, NT, 0);
    presplit_B<<<dim3(32, 64 / 32), 64, 0, stream>>>(Wv, 47, 64, 0);
    gemm_lds<<<dim3((BB*NV)/128, 4), 256, 0, stream>>>(nullptr, nullptr, nullptr, nullptr,
                                                       2, 1, 0, NV, NT);
    presplit_B<<<dim3(32, 128 / 32), 64, 0, stream>>>(Wa, 74, 128, 0);
    gemm_lds<<<dim3((BB*NA)/128, 4), 256, 0, stream>>>(nullptr, nullptr, nullptr, nullptr,
                                                       4, 2, 0, NA, NT + NV);

    for (int l = 0; l < 2; l++) {
        const float* Wg_l = Wg + (size_t)l * NHEAD * HIDD * FD;
        presplit_B<<<dim3(32, 512 / 32), 64, 0, stream>>>(Wg_l, 512, 512, 1);
        gemm_lds<<<dim3((BB*NN)/128, 4), 256, 0, stream>>>(Hthi, Htlo,
            a_src + l * NHEAD * FD, a_dst + l * NHEAD * FD, 16, 3, 1, NN, 0);
        attn_mfma<<<dim3(BB * NHEAD, 5), 256, 0, stream>>>(
            Hthi, Htlo, xbuf, (l == 0) ? 0 : 1);
    }
}

// Round 9
// 345.373 us; speedup vs baseline: 1.1760x; 1.1176x over previous
//
#include <hip/hip_runtime.h>
#include <hip/hip_bf16.h>
#include <math.h>

#define BB 64
#define NN 320
#define NT 256
#define NV 32
#define NA 32
#define HIDD 512
#define NHEAD 8
#define FD 64

typedef __attribute__((ext_vector_type(8))) short bf16x8;
typedef __attribute__((ext_vector_type(4))) float floatx4;

// ---------------------------------------------------------------------------
// device-global scratch (stream-ordered producer->consumer):
//   me_g   : adj-masked exp(edge_logits), built once (in prep_w)
//   fif/fjf: per-(b,head) attention dot products, written by gemm_h epilogue
//   ti/vi/ac planes: presplit inputs, A-FRAGMENT layout [g][kt][lane][8]
//   x planes: node features between layers, same A-fragment layout (nk=16)
//   bw arena: ALL weight matrices in B-fragment layout, one region each:
//     Wt@0(nk24) Wv@393216(nk2) Wa@425984(nk4) Wg0@491520(nk16) Wg1@753664(nk16)
// Every load anywhere is lane-contiguous 16B. Ht lives in d_ws.
// ---------------------------------------------------------------------------
__device__ float me_g[NN * NN];
__device__ float fif_g[512 * NN];
__device__ float fjf_g[512 * NN];
__device__ unsigned short tihi_g[16384 * 768];
__device__ unsigned short tilo_g[16384 * 768];
__device__ unsigned short vihi_g[2048 * 64];
__device__ unsigned short vilo_g[2048 * 64];
__device__ unsigned short achi_g[2048 * 128];
__device__ unsigned short aclo_g[2048 * 128];
__device__ unsigned short xhi_g[20480 * 512];
__device__ unsigned short xlo_g[20480 * 512];
__device__ unsigned short bwhi_g[1015808];
__device__ unsigned short bwlo_g[1015808];

__device__ __forceinline__ void split1(float v, unsigned short& h, unsigned short& l) {
    unsigned u = __float_as_uint(v);
    unsigned hu = u & 0xFFFF0000u;
    float lf = v - __uint_as_float(hu);
    h = (unsigned short)(hu >> 16);
    l = (unsigned short)(__float_as_uint(lf) >> 16);
}
__device__ __forceinline__ unsigned pack2(unsigned short a, unsigned short b) {
    return (unsigned)a | ((unsigned)b << 16);
}

// async global->LDS 16B/lane: LDS dest = wave-uniform base + lane*16,
// global src = per-lane address.
typedef const __attribute__((address_space(1))) unsigned int* gas1_t;
typedef __attribute__((address_space(3))) unsigned int* las3_t;
__device__ __forceinline__ void gload_lds16(const void* g, void* s) {
    __builtin_amdgcn_global_load_lds((gas1_t)(unsigned long long)g,
                                     (las3_t)(unsigned)(unsigned long long)s,
                                     16, 0, 0);
}

// ---------------------------------------------------------------------------
// prep_w: ONE launch for all weight conversions + me. grid (32, 75) x 64thr.
//   y<62: weight regions (tg=x, kt=y-region base) -> bw arena B-frag layout
//   y>=62: me = adj ? exp(elog) : 0
// ---------------------------------------------------------------------------
__global__ __launch_bounds__(64) void prep_w(
    const float* __restrict__ Wt, const float* __restrict__ Wv,
    const float* __restrict__ Wa, const float* __restrict__ Wg,
    const int* __restrict__ adj, const float* __restrict__ elog)
{
    const int x = blockIdx.x, y = blockIdx.y;
    const int lane = threadIdx.x;

    if (y >= 62) {
        const int i4 = (((y - 62) * 32 + x) * 64 + lane) * 4;
        if (i4 < NN * NN) {
            const int4   a = *(const int4*)&adj[i4];
            const float4 e = *(const float4*)&elog[i4];
            float4 m;
            m.x = a.x ? __expf(e.x) : 0.f;
            m.y = a.y ? __expf(e.y) : 0.f;
            m.z = a.z ? __expf(e.z) : 0.f;
            m.w = a.w ? __expf(e.w) : 0.f;
            *(float4*)&me_g[i4] = m;
        }
        return;
    }

    int kt, nk, K, wgm; const float* W; size_t base;
    if (y < 24)      { kt = y;      nk = 24; K = 768; wgm = 0; W = Wt; base = 0; }
    else if (y < 26) { kt = y - 24; nk = 2;  K = 47;  wgm = 0; W = Wv; base = 393216; }
    else if (y < 30) { kt = y - 26; nk = 4;  K = 74;  wgm = 0; W = Wa; base = 425984; }
    else if (y < 46) { kt = y - 30; nk = 16; K = 512; wgm = 1; W = Wg; base = 491520; }
    else             { kt = y - 46; nk = 16; K = 512; wgm = 1; W = Wg + 262144; base = 753664; }

    const int col = x * 16 + (lane & 15);
    const int k0 = kt * 32 + (lane >> 4) * 8;
    unsigned short h[8], l[8];
#pragma unroll
    for (int e = 0; e < 8; e++) {
        const int k = k0 + e;
        float v = 0.f;
        if (k < K) v = wgm ? W[(size_t)(col >> 6) * (512 * 64) + (size_t)k * 64 + (col & 63)]
                           : W[(size_t)k * 512 + col];
        split1(v, h[e], l[e]);
    }
    const size_t o = base + (((size_t)x * nk + kt) * 64 + lane) * 8;
    *(uint4*)&bwhi_g[o] = make_uint4(pack2(h[0], h[1]), pack2(h[2], h[3]),
                                     pack2(h[4], h[5]), pack2(h[6], h[7]));
    *(uint4*)&bwlo_g[o] = make_uint4(pack2(l[0], l[1]), pack2(l[2], l[3]),
                                     pack2(l[4], l[5]), pack2(l[6], l[7]));
}

// ---------------------------------------------------------------------------
// presplit_A body: fp32 [M][K] -> split-bf16 A-fragment planes [M/16][nk][64][8]
// ---------------------------------------------------------------------------
__device__ __forceinline__ void presplitA_body(
    const float* __restrict__ src, int M, int K, int nk,
    unsigned short* __restrict__ dh, unsigned short* __restrict__ dl, unsigned t)
{
    const unsigned lane = t & 63, rec = t >> 6;
    const unsigned kt = rec % (unsigned)nk, g = rec / (unsigned)nk;
    const int row = g * 16 + (lane & 15);
    if (row >= M) return;
    const int k0 = kt * 32 + ((lane >> 4) << 3);
    float v[8];
    if (((K & 3) == 0) && (k0 + 8 <= K)) {
        *(float4*)&v[0] = *(const float4*)&src[(size_t)row * K + k0];
        *(float4*)&v[4] = *(const float4*)&src[(size_t)row * K + k0 + 4];
    } else {
#pragma unroll
        for (int e = 0; e < 8; e++) v[e] = (k0 + e < K) ? src[(size_t)row * K + k0 + e] : 0.f;
    }
    unsigned short h[8], l[8];
#pragma unroll
    for (int e = 0; e < 8; e++) split1(v[e], h[e], l[e]);
    const size_t o = (size_t)t * 8;
    *(uint4*)&dh[o] = make_uint4(pack2(h[0],h[1]), pack2(h[2],h[3]),
                                 pack2(h[4],h[5]), pack2(h[6],h[7]));
    *(uint4*)&dl[o] = make_uint4(pack2(l[0],l[1]), pack2(l[2],l[3]),
                                 pack2(l[4],l[5]), pack2(l[6],l[7]));
}

__global__ __launch_bounds__(256) void presplit_text(const float* __restrict__ src)
{
    presplitA_body(src, 16384, 768, 24, tihi_g, tilo_g, blockIdx.x * 256 + threadIdx.x);
}

// merged visual+acoustic presplit: grid 192 (64 vis + 128 ac)
__global__ __launch_bounds__(256) void prep_va(
    const float* __restrict__ visual, const float* __restrict__ acoustic)
{
    if (blockIdx.x < 64)
        presplitA_body(visual, 2048, 47, 2, vihi_g, vilo_g, blockIdx.x * 256 + threadIdx.x);
    else
        presplitA_body(acoustic, 2048, 74, 4, achi_g, aclo_g, (blockIdx.x - 64) * 256 + threadIdx.x);
}

// ---------------------------------------------------------------------------
// gemm_lds (T3-minimal 2-phase): 128x128 tile, BK=32, 4 waves each 64x64,
// 3-pass split-bf16, double-buffered LDS stage; issue kt+1 loads BEFORE
// computing kt; one vmcnt(0)+barrier per kt (inside __syncthreads).
// merged_va=1: blockIdx.x<16 -> visual, else acoustic (one launch for both).
// b_mode 0: proj epilogue -> x fragment planes via per-wave LDS transpose.
// b_mode 1: gemm_h -> Ht fragment epilogue + fi/fj fold.
// ---------------------------------------------------------------------------
#define GMFMA(AH, AL, BH, BL)                                                  \
  _Pragma("unroll") for (int s = 0; s < 4; s++)                                \
  _Pragma("unroll") for (int t = 0; t < 4; t++) {                              \
      acc[s][t] = __builtin_amdgcn_mfma_f32_16x16x32_bf16(AH[s], BH[t], acc[s][t], 0, 0, 0); \
      acc[s][t] = __builtin_amdgcn_mfma_f32_16x16x32_bf16(AH[s], BL[t], acc[s][t], 0, 0, 0); \
      acc[s][t] = __builtin_amdgcn_mfma_f32_16x16x32_bf16(AL[s], BH[t], acc[s][t], 0, 0, 0); }

__global__ __launch_bounds__(256, 2) void gemm_lds(
    unsigned short* __restrict__ Hthi, unsigned short* __restrict__ Htlo,
    const float* __restrict__ asrc, const float* __restrict__ adst,
    int nk, int a_sel, int bwoff, int b_mode, int rpb, int noff, int merged_va)
{
    __shared__ __align__(16) unsigned short stage[2][32 * 512];   // 64 KB

    int mb = blockIdx.x;
    if (merged_va) {
        if (mb < 16) { a_sel = 1; nk = 2; bwoff = 393216; noff = NT; }
        else { mb -= 16; a_sel = 2; nk = 4; bwoff = 425984; noff = NT + NV; }
    }

    const unsigned short* Ahi = (a_sel == 0) ? tihi_g : (a_sel == 1) ? vihi_g
                              : (a_sel == 2) ? achi_g : xhi_g;
    const unsigned short* Alo = (a_sel == 0) ? tilo_g : (a_sel == 1) ? vilo_g
                              : (a_sel == 2) ? aclo_g : xlo_g;

    const int tid = threadIdx.x, lane = tid & 63, w = tid >> 6;
    const int rw = w >> 1, cw = w & 1;
    const int m0 = mb * 128, n0 = blockIdx.y * 128;
    const int g0 = m0 >> 4, tg0 = n0 >> 4;

    // staging: wave w owns one plane (0:Ahi 1:Alo 2:Bhi 3:Blo), 8 records
    const unsigned short* plane = (w == 0) ? Ahi : (w == 1) ? Alo
                                : (w == 2) ? (bwhi_g + bwoff) : (bwlo_g + bwoff);
    const unsigned rec0 = (w < 2) ? (unsigned)g0 : (unsigned)tg0;
    const unsigned short* wsrc = plane + (size_t)rec0 * nk * 512 + lane * 8;
    const int woff = (w * 8) * 512;

    floatx4 acc[4][4];
#pragma unroll
    for (int s = 0; s < 4; s++)
#pragma unroll
        for (int t = 0; t < 4; t++) acc[s][t] = (floatx4)0.f;

    // prologue: stage kt=0 into buf 0
#pragma unroll
    for (int u = 0; u < 8; u++)
        gload_lds16(wsrc + ((size_t)u * nk) * 512, &stage[0][woff + u * 512]);
    __syncthreads();   // vmcnt(0) drain: buf0 landed

    int cur = 0;
    for (int kt = 0; kt < nk; ++kt) {
        // issue next tile's loads first (fly under this tile's compute)
        if (kt + 1 < nk) {
            unsigned short* nb = &stage[cur ^ 1][woff];
#pragma unroll
            for (int u = 0; u < 8; u++)
                gload_lds16(wsrc + ((size_t)u * nk + kt + 1) * 512, nb + u * 512);
        }
        const unsigned short* sb = &stage[cur][0];
        bf16x8 a_h[4], a_l[4], b_h[4], b_l[4];
#pragma unroll
        for (int s = 0; s < 4; s++) {
            a_h[s] = *(const bf16x8*)&sb[(rw * 4 + s) * 512 + lane * 8];
            a_l[s] = *(const bf16x8*)&sb[(8 + rw * 4 + s) * 512 + lane * 8];
        }
#pragma unroll
        for (int t = 0; t < 4; t++) {
            b_h[t] = *(const bf16x8*)&sb[(16 + cw * 4 + t) * 512 + lane * 8];
            b_l[t] = *(const bf16x8*)&sb[(24 + cw * 4 + t) * 512 + lane * 8];
        }
        GMFMA(a_h, a_l, b_h, b_l);
        __syncthreads();   // drains vmcnt(0) (kt+1 loads) + all ds_reads of buf
        cur ^= 1;
    }

    const int fq = lane & 15, rl = lane >> 4;

    if (b_mode == 0) {
        // ---- proj epilogue: D -> x fragment planes via LDS transpose ----
        float (*sl)[68] = (float (*)[68])(&stage[0][w * 2176]);   // 16x68 fp32
        const int ktg0 = (n0 + cw * 64) >> 5;     // x k-tile base (x nk = 16)
#pragma unroll
        for (int s = 0; s < 4; s++) {
#pragma unroll
            for (int t = 0; t < 4; t++)
#pragma unroll
                for (int r = 0; r < 4; r++)
                    sl[rl * 4 + r][t * 16 + fq] = acc[s][t][r];
            const int grow16 = m0 + rw * 64 + s * 16;
            const int b = grow16 / rpb;
            const int rr = grow16 - b * rpb;
            const unsigned g = (unsigned)b * 20 + (unsigned)((noff + rr) >> 4);
#pragma unroll
            for (int kth = 0; kth < 2; kth++) {
                float f[8];
                *(float4*)&f[0] = *(const float4*)&sl[fq][kth * 32 + rl * 8];
                *(float4*)&f[4] = *(const float4*)&sl[fq][kth * 32 + rl * 8 + 4];
                unsigned short h[8], l[8];
#pragma unroll
                for (int e = 0; e < 8; e++) split1(f[e], h[e], l[e]);
                const size_t o = (((size_t)g * 16 + ktg0 + kth) * 64 + lane) * 8;
                *(uint4*)&xhi_g[o] = make_uint4(pack2(h[0],h[1]), pack2(h[2],h[3]),
                                                pack2(h[4],h[5]), pack2(h[6],h[7]));
                *(uint4*)&xlo_g[o] = make_uint4(pack2(l[0],l[1]), pack2(l[2],l[3]),
                                                pack2(l[4],l[5]), pack2(l[6],l[7]));
            }
        }
    } else {
        // ---- Ht fragment-layout split-bf16 epilogue ----
        const int hd = (n0 + cw * 64) >> 6;
#pragma unroll
        for (int s = 0; s < 4; s++) {
            const int m_s = m0 + rw * 64 + s * 16 + rl * 4;   // rows m_s..m_s+3
            const unsigned b = (unsigned)m_s / 320u;
            const int jb = m_s - b * 320;
            const int ks = jb >> 5;
            const int jg2 = (jb >> 3) & 3;
            const int eb = jb & 7;
            const size_t slabo = (size_t)b * 8 + hd;
#pragma unroll
            for (int t = 0; t < 4; t++) {
                unsigned short h0,h1,h2,h3,l0,l1,l2,l3;
                split1(acc[s][t][0],h0,l0); split1(acc[s][t][1],h1,l1);
                split1(acc[s][t][2],h2,l2); split1(acc[s][t][3],h3,l3);
                const size_t base = (((slabo * 10 + ks) * 4 + t) * 512
                                     + (size_t)(fq | (jg2 << 4)) * 8) + eb;
                *(uint2*)&Hthi[base] = make_uint2(pack2(h0,h1), pack2(h2,h3));
                *(uint2*)&Htlo[base] = make_uint2(pack2(l0,l1), pack2(l2,l3));
            }
        }
        // fi/fj fold: exact fp32 dot(H_row, a_src/a_dst) per (row, head)
        float as4[4], ad4[4];
#pragma unroll
        for (int t = 0; t < 4; t++) {
            as4[t] = asrc[hd * 64 + t * 16 + fq];
            ad4[t] = adst[hd * 64 + t * 16 + fq];
        }
#pragma unroll
        for (int s = 0; s < 4; s++) {
            const int m_s = m0 + rw * 64 + s * 16 + rl * 4;
            const unsigned b = (unsigned)m_s / 320u;
            const int jb = m_s - b * 320;
            float4 fi4, fj4;
#pragma unroll
            for (int r = 0; r < 4; r++) {
                float fi = (acc[s][0][r]*as4[0] + acc[s][1][r]*as4[1])
                         + (acc[s][2][r]*as4[2] + acc[s][3][r]*as4[3]);
                float fj = (acc[s][0][r]*ad4[0] + acc[s][1][r]*ad4[1])
                         + (acc[s][2][r]*ad4[2] + acc[s][3][r]*ad4[3]);
#pragma unroll
                for (int d = 1; d < 16; d <<= 1) {
                    fi += __shfl_xor(fi, d);
                    fj += __shfl_xor(fj, d);
                }
                ((float*)&fi4)[r] = fi; ((float*)&fj4)[r] = fj;
            }
            if (fq == 0) {
                const size_t o = ((size_t)b * 8 + hd) * NN + jb;
                *(float4*)&fif_g[o] = fi4;
                *(float4*)&fjf_g[o] = fj4;
            }
        }
    }
}

// ---------------------------------------------------------------------------
// MFMA GAT attention v7 = r6 structure (grid (512,2), NIP 3/2) with:
//  - B-frags for all 4 f-tiles hoisted BEFORE phase 1 (loads fly under the
//    exp/split VALU) under __launch_bounds__(256,3) (~170-reg cap; est ~155,
//    no spill -- r7's spill was the 128-reg cap of (...,4))
//  - setprio(1) around the now load-free MFMA cluster (T5)
//  - l-reduction via in-wave shfl (r8): no ls[] LDS, no trailing barrier
// final_out=0: elu -> x fragment planes. final_out=1: fp32 -> d_out.
// ---------------------------------------------------------------------------
template<int IP0, int NIP>
__device__ __forceinline__ void attn_body(
    const unsigned short* __restrict__ Hthi, const unsigned short* __restrict__ Htlo,
    float* __restrict__ xout, int final_out, float* fjs,
    float (*slabA)[16][68])
{
    const int bh = blockIdx.x;          // b*8 + hd
    const int hd = bh & 7, b = bh >> 3;
    const int tid = threadIdx.x, lane = tid & 63, w = tid >> 6;
    const int fq = lane & 15, jg = lane >> 4;

    for (int r = tid; r < NN; r += 256) fjs[r] = fjf_g[bh * NN + r];

    float fir[NIP];
#pragma unroll
    for (int ip = 0; ip < NIP; ip++)
        fir[ip] = fif_g[bh * NN + (IP0 + ip) * 64 + (w << 4) + fq];
    __syncthreads();

    floatx4 acc[NIP][4];
#pragma unroll
    for (int ip = 0; ip < NIP; ip++)
#pragma unroll
        for (int nt = 0; nt < 4; nt++) acc[ip][nt] = (floatx4)0.f;
    float lacc[NIP];
#pragma unroll
    for (int ip = 0; ip < NIP; ip++) lacc[ip] = 0.f;

    for (int ks = 0; ks < 10; ks++) {
        // ---- B-frag loads issued first: latency hides under phase-1 VALU ----
        bf16x8 bhf[4], blf[4];
#pragma unroll
        for (int nt = 0; nt < 4; nt++) {
            const unsigned off = (((unsigned)bh * 10 + ks) * 4 + nt) * 512 + (unsigned)lane * 8;
            bhf[nt] = *(const bf16x8*)&Hthi[off];
            blf[nt] = *(const bf16x8*)&Htlo[off];
        }

        const int j8 = ks * 32 + jg * 8;
        const float4 fj0 = *(const float4*)&fjs[j8];
        const float4 fj1 = *(const float4*)&fjs[j8 + 4];

        // ---- phase 1: scores -> exp*me -> split-bf16 A-frags ----
        bf16x8 ahh[NIP], all[NIP];
#pragma unroll
        for (int ip = 0; ip < NIP; ip++) {
            const float fiv = fir[ip];
            const unsigned g = (unsigned)((IP0 + ip) * 64 + (w << 4) + fq) * NN + j8;
            const float4 m0 = *(const float4*)&me_g[g];
            const float4 m1 = *(const float4*)&me_g[g + 4];
            float p[8];
            {
                float s;
                s = fiv + fj0.x; s = fmaxf(s, 0.2f*s); p[0] = __expf(s) * m0.x;
                s = fiv + fj0.y; s = fmaxf(s, 0.2f*s); p[1] = __expf(s) * m0.y;
                s = fiv + fj0.z; s = fmaxf(s, 0.2f*s); p[2] = __expf(s) * m0.z;
                s = fiv + fj0.w; s = fmaxf(s, 0.2f*s); p[3] = __expf(s) * m0.w;
                s = fiv + fj1.x; s = fmaxf(s, 0.2f*s); p[4] = __expf(s) * m1.x;
                s = fiv + fj1.y; s = fmaxf(s, 0.2f*s); p[5] = __expf(s) * m1.y;
                s = fiv + fj1.z; s = fmaxf(s, 0.2f*s); p[6] = __expf(s) * m1.z;
                s = fiv + fj1.w; s = fmaxf(s, 0.2f*s); p[7] = __expf(s) * m1.w;
            }
            lacc[ip] += ((p[0]+p[1]) + (p[2]+p[3])) + ((p[4]+p[5]) + (p[6]+p[7]));

            unsigned short ph[8], pl[8];
#pragma unroll
            for (int e = 0; e < 8; e++) split1(p[e], ph[e], pl[e]);
            union { uint4 u; bf16x8 v; } ua, ul;
            ua.u = make_uint4(pack2(ph[0],ph[1]), pack2(ph[2],ph[3]),
                              pack2(ph[4],ph[5]), pack2(ph[6],ph[7]));
            ul.u = make_uint4(pack2(pl[0],pl[1]), pack2(pl[2],pl[3]),
                              pack2(pl[4],pl[5]), pack2(pl[6],pl[7]));
            ahh[ip] = ua.v; all[ip] = ul.v;
        }

        // ---- phase 2: MFMA cluster, all operands resident, prioritized ----
        __builtin_amdgcn_s_setprio(1);
#pragma unroll
        for (int nt = 0; nt < 4; nt++)
#pragma unroll
            for (int ip = 0; ip < NIP; ip++) {
                acc[ip][nt] = __builtin_amdgcn_mfma_f32_16x16x32_bf16(ahh[ip], bhf[nt], acc[ip][nt], 0, 0, 0);
                acc[ip][nt] = __builtin_amdgcn_mfma_f32_16x16x32_bf16(ahh[ip], blf[nt], acc[ip][nt], 0, 0, 0);
                acc[ip][nt] = __builtin_amdgcn_mfma_f32_16x16x32_bf16(all[ip], bhf[nt], acc[ip][nt], 0, 0, 0);
            }
        __builtin_amdgcn_s_setprio(0);
    }

    // ---- l: reduce over the 4 jg lanes holding the same row (in-wave) ----
#pragma unroll
    for (int ip = 0; ip < NIP; ip++) {
        lacc[ip] += __shfl_xor(lacc[ip], 16);
        lacc[ip] += __shfl_xor(lacc[ip], 32);   // lane x holds l for row (x&15)
    }

    // ---- epilogue: D col(f)=fq, row(i)=jg*4+r ----
    if (final_out) {
#pragma unroll
        for (int ip = 0; ip < NIP; ip++)
#pragma unroll
            for (int r = 0; r < 4; r++) {
                const float lv = __shfl(lacc[ip], jg * 4 + r);
                const float inv = (lv > 0.f) ? 1.f / lv : 0.f;
                const int ib = ((IP0 + ip) * 4 + w) * 16 + jg * 4 + r;
                const size_t ro = ((size_t)(b * NN + ib)) * HIDD + hd * 64;
#pragma unroll
                for (int nt = 0; nt < 4; nt++)
                    xout[ro + nt * 16 + fq] = acc[ip][nt][r] * inv;
            }
    } else {
        // elu + write x fragment planes via per-wave LDS transpose
        float (*sl)[68] = slabA[w];
        const int ktg0 = hd * 2;
#pragma unroll
        for (int ip = 0; ip < NIP; ip++) {
#pragma unroll
            for (int r = 0; r < 4; r++) {
                const float lv = __shfl(lacc[ip], jg * 4 + r);
                const float inv = (lv > 0.f) ? 1.f / lv : 0.f;
#pragma unroll
                for (int nt = 0; nt < 4; nt++) {
                    float vv = acc[ip][nt][r] * inv;
                    vv = (vv > 0.f) ? vv : __expf(vv) - 1.f;   // elu
                    sl[jg * 4 + r][nt * 16 + fq] = vv;
                }
            }
            const unsigned g = (unsigned)b * 20 + (IP0 + ip) * 4 + w;
#pragma unroll
            for (int kth = 0; kth < 2; kth++) {
                float f[8];
                *(float4*)&f[0] = *(const float4*)&sl[fq][kth * 32 + jg * 8];
                *(float4*)&f[4] = *(const float4*)&sl[fq][kth * 32 + jg * 8 + 4];
                unsigned short h[8], l[8];
#pragma unroll
                for (int e = 0; e < 8; e++) split1(f[e], h[e], l[e]);
                const size_t o = (((size_t)g * 16 + ktg0 + kth) * 64 + lane) * 8;
                *(uint4*)&xhi_g[o] = make_uint4(pack2(h[0],h[1]), pack2(h[2],h[3]),
                                                pack2(h[4],h[5]), pack2(h[6],h[7]));
                *(uint4*)&xlo_g[o] = make_uint4(pack2(l[0],l[1]), pack2(l[2],l[3]),
                                                pack2(l[4],l[5]), pack2(l[6],l[7]));
            }
        }
    }
}

__global__ __launch_bounds__(256, 3) void attn_mfma(
    const unsigned short* __restrict__ Hthi, const unsigned short* __restrict__ Htlo,
    float* __restrict__ xout, int final_out)
{
    __shared__ float fjs[NN];
    __shared__ float slabA[4][16][68];
    if (blockIdx.y == 0) attn_body<0, 3>(Hthi, Htlo, xout, final_out, fjs, slabA);
    else                 attn_body<3, 2>(Hthi, Htlo, xout, final_out, fjs, slabA);
}

// ---------------------------------------------------------------------------
// Flow (9 launches): prep_w (all weights + me); presplit_text; prep_va;
// gemm text proj; gemm merged vis+ac; per layer: gemm_h -> Ht(ws)+fi/fj,
// attn -> x planes (l=0, elu) / fp32 d_out (l=1). Strictly stream-ordered.
// ---------------------------------------------------------------------------
extern "C" void kernel_launch(void* const* d_in, const int* in_sizes, int n_in,
                              void* d_out, int out_size, void* d_ws, size_t ws_size,
                              hipStream_t stream)
{
    (void)in_sizes; (void)n_in; (void)out_size; (void)ws_size;
    const float* text     = (const float*)d_in[0];
    const float* visual   = (const float*)d_in[1];
    const float* acoustic = (const float*)d_in[2];
    const int*   adj      = (const int*)d_in[3];
    const float* Wt       = (const float*)d_in[4];
    const float* Wv       = (const float*)d_in[5];
    const float* Wa       = (const float*)d_in[6];
    const float* Wg       = (const float*)d_in[7];
    const float* a_src    = (const float*)d_in[8];
    const float* a_dst    = (const float*)d_in[9];
    const float* elog     = (const float*)d_in[10];

    float* xbuf = (float*)d_out;
    unsigned short* Hthi = (unsigned short*)d_ws;
    unsigned short* Htlo = Hthi + (size_t)512 * 10 * 4 * 512;   // 10,485,760 shorts

    prep_w<<<dim3(32, 75), 64, 0, stream>>>(Wt, Wv, Wa, Wg, adj, elog);
    presplit_text<<<6144, 256, 0, stream>>>(text);
    prep_va<<<192, 256, 0, stream>>>(visual, acoustic);

    // projections -> x planes
    gemm_lds<<<dim3((BB*NT)/128, 4), 256, 0, stream>>>(nullptr, nullptr, nullptr, nullptr,
                                                       24, 0, 0, 0, NT, 0, 0);
    gemm_lds<<<dim3(32, 4), 256, 0, stream>>>(nullptr, nullptr, nullptr, nullptr,
                                              0, 0, 0, 0, 32, 0, 1);   // merged vis+ac

    for (int l = 0; l < 2; l++) {
        gemm_lds<<<dim3((BB*NN)/128, 4), 256, 0, stream>>>(Hthi, Htlo,
            a_src + l * NHEAD * FD, a_dst + l * NHEAD * FD,
            16, 3, (l == 0) ? 491520 : 753664, 1, NN, 0, 0);
        attn_mfma<<<dim3(BB * NHEAD, 2), 256, 0, stream>>>(
            Hthi, Htlo, xbuf, (l == 0) ? 0 : 1);
    }
}

// Round 10
// 341.403 us; speedup vs baseline: 1.1896x; 1.0116x over previous
//
#include <hip/hip_runtime.h>
#include <hip/hip_bf16.h>
#include <math.h>

#define BB 64
#define NN 320
#define NT 256
#define NV 32
#define NA 32
#define HIDD 512
#define NHEAD 8
#define FD 64

typedef __attribute__((ext_vector_type(8))) short bf16x8;
typedef __attribute__((ext_vector_type(4))) float floatx4;

// ---------------------------------------------------------------------------
// device-global scratch (stream-ordered producer->consumer):
//   me_g   : adj-masked exp(edge_logits), built once (in prep_w)
//   fif/fjf: per-(b,head) attention dot products, written by gemm_h epilogue
//   ti/vi/ac planes: presplit inputs, A-FRAGMENT layout [g][kt][lane][8]
//   x planes: node features between layers, same A-fragment layout (nk=16)
//   bw arena: ALL weight matrices in B-fragment layout, one region each:
//     Wt@0(nk24) Wv@393216(nk2) Wa@425984(nk4) Wg0@491520(nk16) Wg1@753664(nk16)
// Every load anywhere is lane-contiguous 16B. Ht lives in d_ws.
// ---------------------------------------------------------------------------
__device__ float me_g[NN * NN];
__device__ float fif_g[512 * NN];
__device__ float fjf_g[512 * NN];
__device__ unsigned short tihi_g[16384 * 768];
__device__ unsigned short tilo_g[16384 * 768];
__device__ unsigned short vihi_g[2048 * 64];
__device__ unsigned short vilo_g[2048 * 64];
__device__ unsigned short achi_g[2048 * 128];
__device__ unsigned short aclo_g[2048 * 128];
__device__ unsigned short xhi_g[20480 * 512];
__device__ unsigned short xlo_g[20480 * 512];
__device__ unsigned short bwhi_g[1015808];
__device__ unsigned short bwlo_g[1015808];

__device__ __forceinline__ void split1(float v, unsigned short& h, unsigned short& l) {
    unsigned u = __float_as_uint(v);
    unsigned hu = u & 0xFFFF0000u;
    float lf = v - __uint_as_float(hu);
    h = (unsigned short)(hu >> 16);
    l = (unsigned short)(__float_as_uint(lf) >> 16);
}
__device__ __forceinline__ unsigned pack2(unsigned short a, unsigned short b) {
    return (unsigned)a | ((unsigned)b << 16);
}

// v_perm split+pack: dst = {u1.hi16, u0.hi16} in one instruction.
// sel 0x07060302: dst bytes {0,1}=src1 bytes {2,3}; dst {2,3}=src0 bytes {6,7}.
#define PSEL 0x07060302u
__device__ __forceinline__ void split_pack8(const float* p, uint4& hi, uint4& lo) {
    unsigned uh[8]; unsigned ul[8];
#pragma unroll
    for (int e = 0; e < 8; e++) {
        const unsigned u = __float_as_uint(p[e]);
        const unsigned hu = u & 0xFFFF0000u;
        ul[e] = __float_as_uint(p[e] - __uint_as_float(hu));
        uh[e] = u;
    }
    hi.x = __builtin_amdgcn_perm(uh[1], uh[0], PSEL);
    hi.y = __builtin_amdgcn_perm(uh[3], uh[2], PSEL);
    hi.z = __builtin_amdgcn_perm(uh[5], uh[4], PSEL);
    hi.w = __builtin_amdgcn_perm(uh[7], uh[6], PSEL);
    lo.x = __builtin_amdgcn_perm(ul[1], ul[0], PSEL);
    lo.y = __builtin_amdgcn_perm(ul[3], ul[2], PSEL);
    lo.z = __builtin_amdgcn_perm(ul[5], ul[4], PSEL);
    lo.w = __builtin_amdgcn_perm(ul[7], ul[6], PSEL);
}
__device__ __forceinline__ void split_pack4(const float* p, uint2& hi, uint2& lo) {
    unsigned uh[4]; unsigned ul[4];
#pragma unroll
    for (int e = 0; e < 4; e++) {
        const unsigned u = __float_as_uint(p[e]);
        const unsigned hu = u & 0xFFFF0000u;
        ul[e] = __float_as_uint(p[e] - __uint_as_float(hu));
        uh[e] = u;
    }
    hi.x = __builtin_amdgcn_perm(uh[1], uh[0], PSEL);
    hi.y = __builtin_amdgcn_perm(uh[3], uh[2], PSEL);
    lo.x = __builtin_amdgcn_perm(ul[1], ul[0], PSEL);
    lo.y = __builtin_amdgcn_perm(ul[3], ul[2], PSEL);
}

// async global->LDS 16B/lane: LDS dest = wave-uniform base + lane*16,
// global src = per-lane address.
typedef const __attribute__((address_space(1))) unsigned int* gas1_t;
typedef __attribute__((address_space(3))) unsigned int* las3_t;
__device__ __forceinline__ void gload_lds16(const void* g, void* s) {
    __builtin_amdgcn_global_load_lds((gas1_t)(unsigned long long)g,
                                     (las3_t)(unsigned)(unsigned long long)s,
                                     16, 0, 0);
}

// ---------------------------------------------------------------------------
// prep_w: ONE launch for all weight conversions + me. grid (32, 75) x 64thr.
//   y<62: weight regions (tg=x, kt=y-region base) -> bw arena B-frag layout
//   y>=62: me = adj ? exp(elog) : 0
// ---------------------------------------------------------------------------
__global__ __launch_bounds__(64) void prep_w(
    const float* __restrict__ Wt, const float* __restrict__ Wv,
    const float* __restrict__ Wa, const float* __restrict__ Wg,
    const int* __restrict__ adj, const float* __restrict__ elog)
{
    const int x = blockIdx.x, y = blockIdx.y;
    const int lane = threadIdx.x;

    if (y >= 62) {
        const int i4 = (((y - 62) * 32 + x) * 64 + lane) * 4;
        if (i4 < NN * NN) {
            const int4   a = *(const int4*)&adj[i4];
            const float4 e = *(const float4*)&elog[i4];
            float4 m;
            m.x = a.x ? __expf(e.x) : 0.f;
            m.y = a.y ? __expf(e.y) : 0.f;
            m.z = a.z ? __expf(e.z) : 0.f;
            m.w = a.w ? __expf(e.w) : 0.f;
            *(float4*)&me_g[i4] = m;
        }
        return;
    }

    int kt, nk, K, wgm; const float* W; size_t base;
    if (y < 24)      { kt = y;      nk = 24; K = 768; wgm = 0; W = Wt; base = 0; }
    else if (y < 26) { kt = y - 24; nk = 2;  K = 47;  wgm = 0; W = Wv; base = 393216; }
    else if (y < 30) { kt = y - 26; nk = 4;  K = 74;  wgm = 0; W = Wa; base = 425984; }
    else if (y < 46) { kt = y - 30; nk = 16; K = 512; wgm = 1; W = Wg; base = 491520; }
    else             { kt = y - 46; nk = 16; K = 512; wgm = 1; W = Wg + 262144; base = 753664; }

    const int col = x * 16 + (lane & 15);
    const int k0 = kt * 32 + (lane >> 4) * 8;
    float v[8];
#pragma unroll
    for (int e = 0; e < 8; e++) {
        const int k = k0 + e;
        v[e] = 0.f;
        if (k < K) v[e] = wgm ? W[(size_t)(col >> 6) * (512 * 64) + (size_t)k * 64 + (col & 63)]
                              : W[(size_t)k * 512 + col];
    }
    uint4 hi, lo; split_pack8(v, hi, lo);
    const size_t o = base + (((size_t)x * nk + kt) * 64 + lane) * 8;
    *(uint4*)&bwhi_g[o] = hi;
    *(uint4*)&bwlo_g[o] = lo;
}

// ---------------------------------------------------------------------------
// presplit_A body: fp32 [M][K] -> split-bf16 A-fragment planes [M/16][nk][64][8]
// ---------------------------------------------------------------------------
__device__ __forceinline__ void presplitA_body(
    const float* __restrict__ src, int M, int K, int nk,
    unsigned short* __restrict__ dh, unsigned short* __restrict__ dl, unsigned t)
{
    const unsigned lane = t & 63, rec = t >> 6;
    const unsigned kt = rec % (unsigned)nk, g = rec / (unsigned)nk;
    const int row = g * 16 + (lane & 15);
    if (row >= M) return;
    const int k0 = kt * 32 + ((lane >> 4) << 3);
    float v[8];
    if (((K & 3) == 0) && (k0 + 8 <= K)) {
        *(float4*)&v[0] = *(const float4*)&src[(size_t)row * K + k0];
        *(float4*)&v[4] = *(const float4*)&src[(size_t)row * K + k0 + 4];
    } else {
#pragma unroll
        for (int e = 0; e < 8; e++) v[e] = (k0 + e < K) ? src[(size_t)row * K + k0 + e] : 0.f;
    }
    uint4 hi, lo; split_pack8(v, hi, lo);
    const size_t o = (size_t)t * 8;
    *(uint4*)&dh[o] = hi;
    *(uint4*)&dl[o] = lo;
}

// merged text+visual+acoustic presplit: grid 6336 (6144 text + 64 vis + 128 ac)
__global__ __launch_bounds__(256) void prep_a(
    const float* __restrict__ text, const float* __restrict__ visual,
    const float* __restrict__ acoustic)
{
    if (blockIdx.x < 6144)
        presplitA_body(text, 16384, 768, 24, tihi_g, tilo_g, blockIdx.x * 256 + threadIdx.x);
    else if (blockIdx.x < 6208)
        presplitA_body(visual, 2048, 47, 2, vihi_g, vilo_g, (blockIdx.x - 6144) * 256 + threadIdx.x);
    else
        presplitA_body(acoustic, 2048, 74, 4, achi_g, aclo_g, (blockIdx.x - 6208) * 256 + threadIdx.x);
}

// ---------------------------------------------------------------------------
// gemm_lds (T3-minimal 2-phase): 128x128 tile, BK=32, 4 waves each 64x64,
// 3-pass split-bf16, double-buffered LDS stage; issue kt+1 loads BEFORE
// computing kt; one vmcnt(0)+barrier per kt (inside __syncthreads).
// merged=2: ONE launch for all projections; grid (160,4):
//   mb<128 text, mb<144 visual, else acoustic.
// b_mode 0: proj epilogue -> x fragment planes via per-wave LDS transpose.
// b_mode 1: gemm_h -> Ht fragment epilogue + fi/fj fold.
// ---------------------------------------------------------------------------
#define GMFMA(AH, AL, BH, BL)                                                  \
  _Pragma("unroll") for (int s = 0; s < 4; s++)                                \
  _Pragma("unroll") for (int t = 0; t < 4; t++) {                              \
      acc[s][t] = __builtin_amdgcn_mfma_f32_16x16x32_bf16(AH[s], BH[t], acc[s][t], 0, 0, 0); \
      acc[s][t] = __builtin_amdgcn_mfma_f32_16x16x32_bf16(AH[s], BL[t], acc[s][t], 0, 0, 0); \
      acc[s][t] = __builtin_amdgcn_mfma_f32_16x16x32_bf16(AL[s], BH[t], acc[s][t], 0, 0, 0); }

__global__ __launch_bounds__(256, 2) void gemm_lds(
    unsigned short* __restrict__ Hthi, unsigned short* __restrict__ Htlo,
    const float* __restrict__ asrc, const float* __restrict__ adst,
    int nk, int a_sel, int bwoff, int b_mode, int rpb, int noff, int merged)
{
    __shared__ __align__(16) unsigned short stage[2][32 * 512];   // 64 KB

    int mb = blockIdx.x;
    if (merged == 2) {
        if (mb < 128)      { a_sel = 0; nk = 24; bwoff = 0;      rpb = NT; noff = 0; }
        else if (mb < 144) { mb -= 128; a_sel = 1; nk = 2; bwoff = 393216; rpb = 32; noff = NT; }
        else               { mb -= 144; a_sel = 2; nk = 4; bwoff = 425984; rpb = 32; noff = NT + NV; }
    }

    const unsigned short* Ahi = (a_sel == 0) ? tihi_g : (a_sel == 1) ? vihi_g
                              : (a_sel == 2) ? achi_g : xhi_g;
    const unsigned short* Alo = (a_sel == 0) ? tilo_g : (a_sel == 1) ? vilo_g
                              : (a_sel == 2) ? aclo_g : xlo_g;

    const int tid = threadIdx.x, lane = tid & 63, w = tid >> 6;
    const int rw = w >> 1, cw = w & 1;
    const int m0 = mb * 128, n0 = blockIdx.y * 128;
    const int g0 = m0 >> 4, tg0 = n0 >> 4;

    // staging: wave w owns one plane (0:Ahi 1:Alo 2:Bhi 3:Blo), 8 records
    const unsigned short* plane = (w == 0) ? Ahi : (w == 1) ? Alo
                                : (w == 2) ? (bwhi_g + bwoff) : (bwlo_g + bwoff);
    const unsigned rec0 = (w < 2) ? (unsigned)g0 : (unsigned)tg0;
    const unsigned short* wsrc = plane + (size_t)rec0 * nk * 512 + lane * 8;
    const int woff = (w * 8) * 512;

    floatx4 acc[4][4];
#pragma unroll
    for (int s = 0; s < 4; s++)
#pragma unroll
        for (int t = 0; t < 4; t++) acc[s][t] = (floatx4)0.f;

    // prologue: stage kt=0 into buf 0
#pragma unroll
    for (int u = 0; u < 8; u++)
        gload_lds16(wsrc + ((size_t)u * nk) * 512, &stage[0][woff + u * 512]);
    __syncthreads();   // vmcnt(0) drain: buf0 landed

    int cur = 0;
    for (int kt = 0; kt < nk; ++kt) {
        // issue next tile's loads first (fly under this tile's compute)
        if (kt + 1 < nk) {
            unsigned short* nb = &stage[cur ^ 1][woff];
#pragma unroll
            for (int u = 0; u < 8; u++)
                gload_lds16(wsrc + ((size_t)u * nk + kt + 1) * 512, nb + u * 512);
        }
        const unsigned short* sb = &stage[cur][0];
        bf16x8 a_h[4], a_l[4], b_h[4], b_l[4];
#pragma unroll
        for (int s = 0; s < 4; s++) {
            a_h[s] = *(const bf16x8*)&sb[(rw * 4 + s) * 512 + lane * 8];
            a_l[s] = *(const bf16x8*)&sb[(8 + rw * 4 + s) * 512 + lane * 8];
        }
#pragma unroll
        for (int t = 0; t < 4; t++) {
            b_h[t] = *(const bf16x8*)&sb[(16 + cw * 4 + t) * 512 + lane * 8];
            b_l[t] = *(const bf16x8*)&sb[(24 + cw * 4 + t) * 512 + lane * 8];
        }
        GMFMA(a_h, a_l, b_h, b_l);
        __syncthreads();   // drains vmcnt(0) (kt+1 loads) + all ds_reads of buf
        cur ^= 1;
    }

    const int fq = lane & 15, rl = lane >> 4;

    if (b_mode == 0) {
        // ---- proj epilogue: D -> x fragment planes via LDS transpose ----
        float (*sl)[68] = (float (*)[68])(&stage[0][w * 2176]);   // 16x68 fp32
        const int ktg0 = (n0 + cw * 64) >> 5;     // x k-tile base (x nk = 16)
#pragma unroll
        for (int s = 0; s < 4; s++) {
#pragma unroll
            for (int t = 0; t < 4; t++)
#pragma unroll
                for (int r = 0; r < 4; r++)
                    sl[rl * 4 + r][t * 16 + fq] = acc[s][t][r];
            const int grow16 = m0 + rw * 64 + s * 16;
            const int b = grow16 / rpb;
            const int rr = grow16 - b * rpb;
            const unsigned g = (unsigned)b * 20 + (unsigned)((noff + rr) >> 4);
#pragma unroll
            for (int kth = 0; kth < 2; kth++) {
                float f[8];
                *(float4*)&f[0] = *(const float4*)&sl[fq][kth * 32 + rl * 8];
                *(float4*)&f[4] = *(const float4*)&sl[fq][kth * 32 + rl * 8 + 4];
                uint4 hi, lo; split_pack8(f, hi, lo);
                const size_t o = (((size_t)g * 16 + ktg0 + kth) * 64 + lane) * 8;
                *(uint4*)&xhi_g[o] = hi;
                *(uint4*)&xlo_g[o] = lo;
            }
        }
    } else {
        // ---- Ht fragment-layout split-bf16 epilogue ----
        const int hd = (n0 + cw * 64) >> 6;
#pragma unroll
        for (int s = 0; s < 4; s++) {
            const int m_s = m0 + rw * 64 + s * 16 + rl * 4;   // rows m_s..m_s+3
            const unsigned b = (unsigned)m_s / 320u;
            const int jb = m_s - b * 320;
            const int ks = jb >> 5;
            const int jg2 = (jb >> 3) & 3;
            const int eb = jb & 7;
            const size_t slabo = (size_t)b * 8 + hd;
#pragma unroll
            for (int t = 0; t < 4; t++) {
                float f[4] = { acc[s][t][0], acc[s][t][1], acc[s][t][2], acc[s][t][3] };
                uint2 hi, lo; split_pack4(f, hi, lo);
                const size_t base = (((slabo * 10 + ks) * 4 + t) * 512
                                     + (size_t)(fq | (jg2 << 4)) * 8) + eb;
                *(uint2*)&Hthi[base] = hi;
                *(uint2*)&Htlo[base] = lo;
            }
        }
        // fi/fj fold: exact fp32 dot(H_row, a_src/a_dst) per (row, head)
        float as4[4], ad4[4];
#pragma unroll
        for (int t = 0; t < 4; t++) {
            as4[t] = asrc[hd * 64 + t * 16 + fq];
            ad4[t] = adst[hd * 64 + t * 16 + fq];
        }
#pragma unroll
        for (int s = 0; s < 4; s++) {
            const int m_s = m0 + rw * 64 + s * 16 + rl * 4;
            const unsigned b = (unsigned)m_s / 320u;
            const int jb = m_s - b * 320;
            float4 fi4, fj4;
#pragma unroll
            for (int r = 0; r < 4; r++) {
                float fi = (acc[s][0][r]*as4[0] + acc[s][1][r]*as4[1])
                         + (acc[s][2][r]*as4[2] + acc[s][3][r]*as4[3]);
                float fj = (acc[s][0][r]*ad4[0] + acc[s][1][r]*ad4[1])
                         + (acc[s][2][r]*ad4[2] + acc[s][3][r]*ad4[3]);
#pragma unroll
                for (int d = 1; d < 16; d <<= 1) {
                    fi += __shfl_xor(fi, d);
                    fj += __shfl_xor(fj, d);
                }
                ((float*)&fi4)[r] = fi; ((float*)&fj4)[r] = fj;
            }
            if (fq == 0) {
                const size_t o = ((size_t)b * 8 + hd) * NN + jb;
                *(float4*)&fif_g[o] = fi4;
                *(float4*)&fjf_g[o] = fj4;
            }
        }
    }
}

// ---------------------------------------------------------------------------
// MFMA GAT attention (r9 structure): grid (512,2), NIP 3/2, (256,3).
//  - B-frags for all 4 f-tiles hoisted BEFORE phase 1 (fly under exp/split)
//  - v_perm split+pack (bit-identical, ~40% fewer phase-1 pack ops)
//  - setprio(1) around the load-free MFMA cluster (T5)
//  - l-reduction via in-wave shfl (no ls[] LDS, no trailing barrier)
// final_out=0: elu -> x fragment planes. final_out=1: fp32 -> d_out.
// ---------------------------------------------------------------------------
template<int IP0, int NIP>
__device__ __forceinline__ void attn_body(
    const unsigned short* __restrict__ Hthi, const unsigned short* __restrict__ Htlo,
    float* __restrict__ xout, int final_out, float* fjs,
    float (*slabA)[16][68])
{
    const int bh = blockIdx.x;          // b*8 + hd
    const int hd = bh & 7, b = bh >> 3;
    const int tid = threadIdx.x, lane = tid & 63, w = tid >> 6;
    const int fq = lane & 15, jg = lane >> 4;

    for (int r = tid; r < NN; r += 256) fjs[r] = fjf_g[bh * NN + r];

    float fir[NIP];
#pragma unroll
    for (int ip = 0; ip < NIP; ip++)
        fir[ip] = fif_g[bh * NN + (IP0 + ip) * 64 + (w << 4) + fq];
    __syncthreads();

    floatx4 acc[NIP][4];
#pragma unroll
    for (int ip = 0; ip < NIP; ip++)
#pragma unroll
        for (int nt = 0; nt < 4; nt++) acc[ip][nt] = (floatx4)0.f;
    float lacc[NIP];
#pragma unroll
    for (int ip = 0; ip < NIP; ip++) lacc[ip] = 0.f;

    for (int ks = 0; ks < 10; ks++) {
        // ---- B-frag loads issued first: latency hides under phase-1 VALU ----
        bf16x8 bhf[4], blf[4];
#pragma unroll
        for (int nt = 0; nt < 4; nt++) {
            const unsigned off = (((unsigned)bh * 10 + ks) * 4 + nt) * 512 + (unsigned)lane * 8;
            bhf[nt] = *(const bf16x8*)&Hthi[off];
            blf[nt] = *(const bf16x8*)&Htlo[off];
        }

        const int j8 = ks * 32 + jg * 8;
        const float4 fj0 = *(const float4*)&fjs[j8];
        const float4 fj1 = *(const float4*)&fjs[j8 + 4];

        // ---- phase 1: scores -> exp*me -> split-bf16 A-frags ----
        bf16x8 ahh[NIP], all[NIP];
#pragma unroll
        for (int ip = 0; ip < NIP; ip++) {
            const float fiv = fir[ip];
            const unsigned g = (unsigned)((IP0 + ip) * 64 + (w << 4) + fq) * NN + j8;
            const float4 m0 = *(const float4*)&me_g[g];
            const float4 m1 = *(const float4*)&me_g[g + 4];
            float p[8];
            {
                float s;
                s = fiv + fj0.x; s = fmaxf(s, 0.2f*s); p[0] = __expf(s) * m0.x;
                s = fiv + fj0.y; s = fmaxf(s, 0.2f*s); p[1] = __expf(s) * m0.y;
                s = fiv + fj0.z; s = fmaxf(s, 0.2f*s); p[2] = __expf(s) * m0.z;
                s = fiv + fj0.w; s = fmaxf(s, 0.2f*s); p[3] = __expf(s) * m0.w;
                s = fiv + fj1.x; s = fmaxf(s, 0.2f*s); p[4] = __expf(s) * m1.x;
                s = fiv + fj1.y; s = fmaxf(s, 0.2f*s); p[5] = __expf(s) * m1.y;
                s = fiv + fj1.z; s = fmaxf(s, 0.2f*s); p[6] = __expf(s) * m1.z;
                s = fiv + fj1.w; s = fmaxf(s, 0.2f*s); p[7] = __expf(s) * m1.w;
            }
            lacc[ip] += ((p[0]+p[1]) + (p[2]+p[3])) + ((p[4]+p[5]) + (p[6]+p[7]));

            union { uint4 u; bf16x8 v; } ua, ul;
            split_pack8(p, ua.u, ul.u);
            ahh[ip] = ua.v; all[ip] = ul.v;
        }

        // ---- phase 2: MFMA cluster, all operands resident, prioritized ----
        __builtin_amdgcn_s_setprio(1);
#pragma unroll
        for (int nt = 0; nt < 4; nt++)
#pragma unroll
            for (int ip = 0; ip < NIP; ip++) {
                acc[ip][nt] = __builtin_amdgcn_mfma_f32_16x16x32_bf16(ahh[ip], bhf[nt], acc[ip][nt], 0, 0, 0);
                acc[ip][nt] = __builtin_amdgcn_mfma_f32_16x16x32_bf16(ahh[ip], blf[nt], acc[ip][nt], 0, 0, 0);
                acc[ip][nt] = __builtin_amdgcn_mfma_f32_16x16x32_bf16(all[ip], bhf[nt], acc[ip][nt], 0, 0, 0);
            }
        __builtin_amdgcn_s_setprio(0);
    }

    // ---- l: reduce over the 4 jg lanes holding the same row (in-wave) ----
#pragma unroll
    for (int ip = 0; ip < NIP; ip++) {
        lacc[ip] += __shfl_xor(lacc[ip], 16);
        lacc[ip] += __shfl_xor(lacc[ip], 32);   // lane x holds l for row (x&15)
    }

    // ---- epilogue: D col(f)=fq, row(i)=jg*4+r ----
    if (final_out) {
#pragma unroll
        for (int ip = 0; ip < NIP; ip++)
#pragma unroll
            for (int r = 0; r < 4; r++) {
                const float lv = __shfl(lacc[ip], jg * 4 + r);
                const float inv = (lv > 0.f) ? 1.f / lv : 0.f;
                const int ib = ((IP0 + ip) * 4 + w) * 16 + jg * 4 + r;
                const size_t ro = ((size_t)(b * NN + ib)) * HIDD + hd * 64;
#pragma unroll
                for (int nt = 0; nt < 4; nt++)
                    xout[ro + nt * 16 + fq] = acc[ip][nt][r] * inv;
            }
    } else {
        // elu + write x fragment planes via per-wave LDS transpose
        float (*sl)[68] = slabA[w];
        const int ktg0 = hd * 2;
#pragma unroll
        for (int ip = 0; ip < NIP; ip++) {
#pragma unroll
            for (int r = 0; r < 4; r++) {
                const float lv = __shfl(lacc[ip], jg * 4 + r);
                const float inv = (lv > 0.f) ? 1.f / lv : 0.f;
#pragma unroll
                for (int nt = 0; nt < 4; nt++) {
                    float vv = acc[ip][nt][r] * inv;
                    vv = (vv > 0.f) ? vv : __expf(vv) - 1.f;   // elu
                    sl[jg * 4 + r][nt * 16 + fq] = vv;
                }
            }
            const unsigned g = (unsigned)b * 20 + (IP0 + ip) * 4 + w;
#pragma unroll
            for (int kth = 0; kth < 2; kth++) {
                float f[8];
                *(float4*)&f[0] = *(const float4*)&sl[fq][kth * 32 + jg * 8];
                *(float4*)&f[4] = *(const float4*)&sl[fq][kth * 32 + jg * 8 + 4];
                uint4 hi, lo; split_pack8(f, hi, lo);
                const size_t o = (((size_t)g * 16 + ktg0 + kth) * 64 + lane) * 8;
                *(uint4*)&xhi_g[o] = hi;
                *(uint4*)&xlo_g[o] = lo;
            }
        }
    }
}

__global__ __launch_bounds__(256, 3) void attn_mfma(
    const unsigned short* __restrict__ Hthi, const unsigned short* __restrict__ Htlo,
    float* __restrict__ xout, int final_out)
{
    __shared__ float fjs[NN];
    __shared__ float slabA[4][16][68];
    if (blockIdx.y == 0) attn_body<0, 3>(Hthi, Htlo, xout, final_out, fjs, slabA);
    else                 attn_body<3, 2>(Hthi, Htlo, xout, final_out, fjs, slabA);
}

// ---------------------------------------------------------------------------
// Flow (7 launches): prep_w (weights + me); prep_a (all input presplits);
// gemm_lds merged=2 (all three projections); per layer: gemm_h -> Ht+fi/fj,
// attn -> x planes (l=0, elu) / fp32 d_out (l=1). Strictly stream-ordered.
// ---------------------------------------------------------------------------
extern "C" void kernel_launch(void* const* d_in, const int* in_sizes, int n_in,
                              void* d_out, int out_size, void* d_ws, size_t ws_size,
                              hipStream_t stream)
{
    (void)in_sizes; (void)n_in; (void)out_size; (void)ws_size;
    const float* text     = (const float*)d_in[0];
    const float* visual   = (const float*)d_in[1];
    const float* acoustic = (const float*)d_in[2];
    const int*   adj      = (const int*)d_in[3];
    const float* Wt       = (const float*)d_in[4];
    const float* Wv       = (const float*)d_in[5];
    const float* Wa       = (const float*)d_in[6];
    const float* Wg       = (const float*)d_in[7];
    const float* a_src    = (const float*)d_in[8];
    const float* a_dst    = (const float*)d_in[9];
    const float* elog     = (const float*)d_in[10];

    float* xbuf = (float*)d_out;
    unsigned short* Hthi = (unsigned short*)d_ws;
    unsigned short* Htlo = Hthi + (size_t)512 * 10 * 4 * 512;   // 10,485,760 shorts

    prep_w<<<dim3(32, 75), 64, 0, stream>>>(Wt, Wv, Wa, Wg, adj, elog);
    prep_a<<<6336, 256, 0, stream>>>(text, visual, acoustic);

    // all projections -> x planes (one launch: 128 text + 16 vis + 16 ac m-blocks)
    gemm_lds<<<dim3(160, 4), 256, 0, stream>>>(nullptr, nullptr, nullptr, nullptr,
                                               0, 0, 0, 0, 0, 0, 2);

    for (int l = 0; l < 2; l++) {
        gemm_lds<<<dim3((BB*NN)/128, 4), 256, 0, stream>>>(Hthi, Htlo,
            a_src + l * NHEAD * FD, a_dst + l * NHEAD * FD,
            16, 3, (l == 0) ? 491520 : 753664, 1, NN, 0, 0);
        attn_mfma<<<dim3(BB * NHEAD, 2), 256, 0, stream>>>(
            Hthi, Htlo, xbuf, (l == 0) ? 0 : 1);
    }
}